// Round 12
// baseline (12597.425 us; speedup 1.0000x reference)
//
#include <hip/hip_runtime.h>
#include <math.h>

#define VOCAB 32000
#define EMBD  512
#define HID   1024
#define BATCH 32
#define SEQ   64
#define TENC  64
#define NSTEP 63
#define G4    4096
#define NTILE_N 250          // 32000/128
#define NTILES  8000         // 32 m-tiles x 250 n-tiles

typedef __attribute__((ext_vector_type(8))) short short8;
typedef __attribute__((ext_vector_type(4))) float f32x4;
typedef __attribute__((ext_vector_type(4))) unsigned short us4;
typedef unsigned short u16;

__device__ __forceinline__ float4 ld4(const float* p) {
  return *reinterpret_cast<const float4*>(p);
}
__device__ __forceinline__ u16 f2bf(float x) {
  unsigned u = __float_as_uint(x);
  return (u16)((u + 0x7fffu + ((u >> 16) & 1u)) >> 16);
}
__device__ __forceinline__ float bf2f(u16 h) {
  return __uint_as_float(((unsigned)h) << 16);
}

// ===== logits args (shared by in-loop tiles and epilogue) =====
struct LM {
  const u16* Ahi; const u16* Alo;
  const u16* Bhi; const u16* Blo;
  const float* bo; float* out;
};

// ===== one 64m x 128n logits tile, split-bf16 MFMA (validated layout) =====
// smemf: >= 6144 floats (24KB). 256 threads.
__device__ void logits_tile(const LM& P, int tile, float* smemf) {
  u16* sA = (u16*)smemf;          // [2][4][64][8]
  u16* sB = sA + 4096;            // [2][4][128][8]
  const int mi = tile / NTILE_N, ni = tile % NTILE_N;
  const int m0 = mi * 64, n0 = ni * 128;
  const int tid = threadIdx.x;
  const int w = tid >> 6, l = tid & 63;
  const int mb = (w & 1) * 32, nb = (w >> 1) * 64;
  f32x4 acc[2][4];
  #pragma unroll
  for (int mt = 0; mt < 2; ++mt)
    #pragma unroll
    for (int nt = 0; nt < 4; ++nt) acc[mt][nt] = (f32x4){0.f,0.f,0.f,0.f};

  const int arow = tid >> 2, akg = tid & 3;
  const int brow = tid >> 1, bkg = (tid & 1) * 2;
  short8 pah, pal, pbh0, pbh1, pbl0, pbl1;
  {
    const size_t ao = (size_t)(m0 + arow)*HID + akg*8;
    const size_t bo0 = (size_t)(n0 + brow)*HID + bkg*8;
    pah  = *reinterpret_cast<const short8*>(P.Ahi + ao);
    pal  = *reinterpret_cast<const short8*>(P.Alo + ao);
    pbh0 = *reinterpret_cast<const short8*>(P.Bhi + bo0);
    pbh1 = *reinterpret_cast<const short8*>(P.Bhi + bo0 + 8);
    pbl0 = *reinterpret_cast<const short8*>(P.Blo + bo0);
    pbl1 = *reinterpret_cast<const short8*>(P.Blo + bo0 + 8);
  }
  for (int kc = 0; kc < 32; ++kc) {
    __syncthreads();
    *reinterpret_cast<short8*>(sA + ((0*4 + akg)*64 + arow)*8) = pah;
    *reinterpret_cast<short8*>(sA + ((1*4 + akg)*64 + arow)*8) = pal;
    *reinterpret_cast<short8*>(sB + ((0*4 + bkg  )*128 + brow)*8) = pbh0;
    *reinterpret_cast<short8*>(sB + ((0*4 + bkg+1)*128 + brow)*8) = pbh1;
    *reinterpret_cast<short8*>(sB + ((1*4 + bkg  )*128 + brow)*8) = pbl0;
    *reinterpret_cast<short8*>(sB + ((1*4 + bkg+1)*128 + brow)*8) = pbl1;
    __syncthreads();
    if (kc + 1 < 32) {
      const size_t ao = (size_t)(m0 + arow)*HID + (kc+1)*32 + akg*8;
      const size_t bo0 = (size_t)(n0 + brow)*HID + (kc+1)*32 + bkg*8;
      pah  = *reinterpret_cast<const short8*>(P.Ahi + ao);
      pal  = *reinterpret_cast<const short8*>(P.Alo + ao);
      pbh0 = *reinterpret_cast<const short8*>(P.Bhi + bo0);
      pbh1 = *reinterpret_cast<const short8*>(P.Bhi + bo0 + 8);
      pbl0 = *reinterpret_cast<const short8*>(P.Blo + bo0);
      pbl1 = *reinterpret_cast<const short8*>(P.Blo + bo0 + 8);
    }
    const int kg = l >> 4, rr = l & 15;
    short8 ah[2], al[2];
    #pragma unroll
    for (int mt = 0; mt < 2; ++mt) {
      ah[mt] = *reinterpret_cast<const short8*>(sA + ((0*4 + kg)*64 + mb + mt*16 + rr)*8);
      al[mt] = *reinterpret_cast<const short8*>(sA + ((1*4 + kg)*64 + mb + mt*16 + rr)*8);
    }
    #pragma unroll
    for (int nt = 0; nt < 4; ++nt) {
      const short8 bh = *reinterpret_cast<const short8*>(sB + ((0*4 + kg)*128 + nb + nt*16 + rr)*8);
      const short8 bl = *reinterpret_cast<const short8*>(sB + ((1*4 + kg)*128 + nb + nt*16 + rr)*8);
      #pragma unroll
      for (int mt = 0; mt < 2; ++mt) {
        acc[mt][nt] = __builtin_amdgcn_mfma_f32_16x16x32_bf16(ah[mt], bh, acc[mt][nt], 0, 0, 0);
        acc[mt][nt] = __builtin_amdgcn_mfma_f32_16x16x32_bf16(ah[mt], bl, acc[mt][nt], 0, 0, 0);
        acc[mt][nt] = __builtin_amdgcn_mfma_f32_16x16x32_bf16(al[mt], bh, acc[mt][nt], 0, 0, 0);
      }
    }
  }
  #pragma unroll
  for (int mt = 0; mt < 2; ++mt) {
    #pragma unroll
    for (int nt = 0; nt < 4; ++nt) {
      #pragma unroll
      for (int r = 0; r < 4; ++r) {
        const int row = m0 + mb + mt*16 + (l >> 4)*4 + r;
        const int col = n0 + nb + nt*16 + (l & 15);
        if (row < NSTEP*BATCH)
          P.out[(size_t)row*VOCAB + col] = acc[mt][nt][r] + P.bo[col];
      }
    }
  }
}

__global__ __launch_bounds__(256) void logits_tiles_k(LM P, int qbase) {
  __shared__ float smem[6144];
  logits_tile(P, qbase + blockIdx.x, smem);
}

// ===== MFMA 32x32 tile core (unchanged from R11, validated) =====
template<int MODE>
__device__ __forceinline__ void mfma32(
    const u16* __restrict__ Xahi, const u16* __restrict__ Xalo,
    const u16* __restrict__ Xbhi, const u16* __restrict__ Xblo,
    const u16* __restrict__ Whi,  const u16* __restrict__ Wlo,
    int nt, float* res)
{
  const int tid = threadIdx.x;
  const int w = tid >> 6, l = tid & 63;
  const int c = l & 15, koct = l >> 4;
  constexpr int K   = (MODE == 0) ? 2048 : 1024;
  constexpr int WS  = (MODE == 0) ? 2048 : 1024;
  constexpr int SPW = K / 32 / 4;
  const int r0 = c, r1 = 16 + c;
  const int wr0 = (MODE == 0) ? ((r0 >> 3)*1024 + nt*8 + (r0 & 7)) : (nt*32 + r0);
  const int wr1 = (MODE == 0) ? ((r1 >> 3)*1024 + nt*8 + (r1 & 7)) : (nt*32 + r1);
  const u16* bh0 = Whi + (size_t)wr0 * WS;
  const u16* bh1 = Whi + (size_t)wr1 * WS;
  const u16* bl0 = Wlo + (size_t)wr0 * WS;
  const u16* bl1 = Wlo + (size_t)wr1 * WS;

  auto ldA = [&](int m, int kg, int lo) -> short8 {
    const u16* base;
    if (MODE == 0 && kg >= 1024) base = lo ? Xblo : Xbhi;
    else                         base = lo ? Xalo : Xahi;
    const int b = m*16 + c;
    return *reinterpret_cast<const short8*>(base + b*1024 + (kg & 1023));
  };

  f32x4 acc[2][2];
  #pragma unroll
  for (int m = 0; m < 2; ++m)
    #pragma unroll
    for (int n = 0; n < 2; ++n) acc[m][n] = (f32x4){0.f,0.f,0.f,0.f};

  const int s0 = w * SPW;
  short8 Ah[2], Al[2], Bh[2], Bl[2];
  {
    const int kg = s0*32 + koct*8;
    Ah[0]=ldA(0,kg,0); Ah[1]=ldA(1,kg,0); Al[0]=ldA(0,kg,1); Al[1]=ldA(1,kg,1);
    Bh[0]=*reinterpret_cast<const short8*>(bh0+kg);
    Bh[1]=*reinterpret_cast<const short8*>(bh1+kg);
    Bl[0]=*reinterpret_cast<const short8*>(bl0+kg);
    Bl[1]=*reinterpret_cast<const short8*>(bl1+kg);
  }
  for (int s = s0; s < s0 + SPW; ++s) {
    short8 nAh[2], nAl[2], nBh[2], nBl[2];
    if (s + 1 < s0 + SPW) {
      const int kg = (s+1)*32 + koct*8;
      nAh[0]=ldA(0,kg,0); nAh[1]=ldA(1,kg,0); nAl[0]=ldA(0,kg,1); nAl[1]=ldA(1,kg,1);
      nBh[0]=*reinterpret_cast<const short8*>(bh0+kg);
      nBh[1]=*reinterpret_cast<const short8*>(bh1+kg);
      nBl[0]=*reinterpret_cast<const short8*>(bl0+kg);
      nBl[1]=*reinterpret_cast<const short8*>(bl1+kg);
    }
    #pragma unroll
    for (int n = 0; n < 2; ++n)
      #pragma unroll
      for (int m = 0; m < 2; ++m) {
        acc[m][n] = __builtin_amdgcn_mfma_f32_16x16x32_bf16(Ah[m], Bh[n], acc[m][n], 0, 0, 0);
        acc[m][n] = __builtin_amdgcn_mfma_f32_16x16x32_bf16(Ah[m], Bl[n], acc[m][n], 0, 0, 0);
        acc[m][n] = __builtin_amdgcn_mfma_f32_16x16x32_bf16(Al[m], Bh[n], acc[m][n], 0, 0, 0);
      }
    #pragma unroll
    for (int i = 0; i < 2; ++i) { Ah[i]=nAh[i]; Al[i]=nAl[i]; Bh[i]=nBh[i]; Bl[i]=nBl[i]; }
  }
  #pragma unroll
  for (int m = 0; m < 2; ++m)
    #pragma unroll
    for (int n = 0; n < 2; ++n)
      #pragma unroll
      for (int r = 0; r < 4; ++r) {
        const int b = m*16 + koct*4 + r;
        const int rr = n*16 + c;
        res[w*1056 + b*33 + rr] = acc[m][n][r];
      }
}

// ===== L1/L2: gates + cell (+ optional logits tail blocks) =====
struct GKM {
  const u16 *Xahi, *Xalo, *Xbhi, *Xblo;
  const u16 *Whi, *Wlo;
  const float* bsum; const float* gembt;
  float* c; u16 *hhi; u16 *hlo;
  LM lm; int qbase, qcount;
};

template<int HASGEMB>
__global__ __launch_bounds__(256) void gates_mfma_k(GKM P) {
  __shared__ float smem[6144];
  if (blockIdx.x >= 128) {
    const int e = blockIdx.x - 128;
    if (e < P.qcount) logits_tile(P.lm, P.qbase + e, smem);
    return;
  }
  float* res = smem;
  mfma32<0>(P.Xahi, P.Xalo, P.Xbhi, P.Xblo, P.Whi, P.Wlo, blockIdx.x, res);
  __syncthreads();
  const int tid = threadIdx.x;
  const int b = tid >> 3, j = tid & 7;
  const int n = blockIdx.x*8 + j;
  float g4[4];
  #pragma unroll
  for (int g = 0; g < 4; ++g) {
    const int r = g*8 + j;
    float s = P.bsum[g*1024 + n]
            + res[b*33+r] + res[1056 + b*33+r] + res[2112 + b*33+r] + res[3168 + b*33+r];
    if (HASGEMB) s += P.gembt[(size_t)b*G4 + g*1024 + n];
    g4[g] = s;
  }
  const float si = 1.f/(1.f+expf(-g4[0]));
  const float sf = 1.f/(1.f+expf(-g4[1]));
  const float so = 1.f/(1.f+expf(-g4[3]));
  const int i = b*HID + n;
  const float cn = sf*P.c[i] + si*tanhf(g4[2]);
  P.c[i] = cn;
  const float h = so*tanhf(cn);
  const u16 hh = f2bf(h);
  P.hhi[i] = hh;
  P.hlo[i] = f2bf(h - bf2f(hh));
}

// ===== L3: proj (+ logits tail) =====
struct PKM {
  const u16 *Xhi, *Xlo; const u16 *Whi, *Wlo; float* Pq;
  LM lm; int qbase, qcount;
};

__global__ __launch_bounds__(256) void proj_mfma_k(PKM P) {
  __shared__ float smem[6144];
  if (blockIdx.x >= 64) {
    const int e = blockIdx.x - 64;
    if (e < P.qcount) logits_tile(P.lm, P.qbase + e, smem);
    return;
  }
  float* res = smem;
  mfma32<1>(P.Xhi, P.Xlo, nullptr, nullptr, P.Whi, P.Wlo, blockIdx.x, res);
  __syncthreads();
  const int tid = threadIdx.x;
  #pragma unroll
  for (int q = 0; q < 4; ++q) {
    const int o = q*256 + tid;
    const int b = o >> 5, r = o & 31;
    const float s = res[b*33+r] + res[1056 + b*33+r]
                  + res[2112 + b*33+r] + res[3168 + b*33+r];
    P.Pq[(size_t)b*2048 + blockIdx.x*32 + r] = s;
  }
}

// ===== L4: attention, 256 thr (+ logits tail) =====
struct AKM {
  const float* Pq; const float* PreAC; const float* va; const float* bc;
  u16* AHthi; u16* AHtlo;
  LM lm; int qbase, qcount;
};

__global__ __launch_bounds__(256) void attn_k(AKM P) {
  __shared__ float smem[6144];
  if (blockIdx.x >= 32) {
    const int e = blockIdx.x - 32;
    if (e < P.qcount) logits_tile(P.lm, P.qbase + e, smem);
    return;
  }
  float* QS  = smem;            // [1024]
  float* sw  = smem + 1024;     // [64]
  float* W64 = smem + 1088;     // [64]
  const int b = blockIdx.x;
  const int tid = threadIdx.x;
  #pragma unroll
  for (int q = 0; q < 4; ++q) QS[q*256 + tid] = P.Pq[(size_t)b*2048 + q*256 + tid];
  __syncthreads();
  const int lane = tid & 63, wid = tid >> 6;    // 4 waves
  float vreg[16];
  #pragma unroll
  for (int i2 = 0; i2 < 16; ++i2) vreg[i2] = P.va[lane + 64*i2];
  #pragma unroll
  for (int j = 0; j < 16; ++j) {
    const int te = wid*16 + j;
    const float* pr = P.PreAC + ((size_t)te*BATCH + b)*2048;
    float s = 0.f;
    #pragma unroll
    for (int i2 = 0; i2 < 16; ++i2) {
      const int idx = lane + 64*i2;
      s += vreg[i2] * tanhf(QS[idx] + pr[idx]);
    }
    #pragma unroll
    for (int off = 32; off; off >>= 1) s += __shfl_xor(s, off);
    if (lane == 0) sw[te] = s;
  }
  __syncthreads();
  if (tid < TENC) {
    const float v = sw[tid];
    float mx = v;
    #pragma unroll
    for (int off = 32; off; off >>= 1) mx = fmaxf(mx, __shfl_xor(mx, off));
    const float e = expf(v - mx);
    float sum = e;
    #pragma unroll
    for (int off = 32; off; off >>= 1) sum += __shfl_xor(sum, off);
    W64[tid] = e / sum;
  }
  __syncthreads();
  #pragma unroll
  for (int q = 0; q < 4; ++q) {
    const int hh = q*256 + tid;
    float acc = 0.f;
    #pragma unroll 8
    for (int te = 0; te < TENC; ++te)
      acc += W64[te] * P.PreAC[((size_t)te*BATCH + b)*2048 + HID + hh];
    const float hc = P.Pq[(size_t)b*2048 + HID + hh] + P.bc[hh];
    const float ah = tanhf(acc + hc);
    const u16 ahh = f2bf(ah);
    P.AHthi[(size_t)b*HID + hh] = ahh;
    P.AHtlo[(size_t)b*HID + hh] = f2bf(ah - bf2f(ahh));
  }
}

// ===== weight pack + hi/lo split (one-time) =====
template<int MODE>
__global__ __launch_bounds__(256) void pack_k(const float* __restrict__ A,
                                              const float* __restrict__ B,
                                              u16* __restrict__ hi, u16* __restrict__ lo) {
  constexpr int ROWS = (MODE == 2) ? 2048 : 4096;
  constexpr int K    = (MODE == 2) ? 1024 : 2048;
  const size_t total = (size_t)ROWS * (K/4);
  for (size_t i = (size_t)blockIdx.x*256 + threadIdx.x; i < total;
       i += (size_t)gridDim.x*256) {
    const int row = (int)(i / (K/4));
    const int k = (int)(i % (K/4)) * 4;
    float4 v;
    if (MODE == 0) v = (k < 1024) ? ld4(A + (size_t)row*1536 + 512 + k)
                                  : ld4(B + (size_t)row*1024 + (k - 1024));
    else if (MODE == 1) v = (k < 1024) ? ld4(A + (size_t)row*1024 + k)
                                       : ld4(B + (size_t)row*1024 + (k - 1024));
    else v = (row < 1024) ? ld4(A + (size_t)row*2048 + k)
                          : ld4(B + (size_t)(row - 1024)*2048 + k);
    us4 h, l;
    h.x = f2bf(v.x); l.x = f2bf(v.x - bf2f(h.x));
    h.y = f2bf(v.y); l.y = f2bf(v.y - bf2f(h.y));
    h.z = f2bf(v.z); l.z = f2bf(v.z - bf2f(h.z));
    h.w = f2bf(v.w); l.w = f2bf(v.w - bf2f(h.w));
    *reinterpret_cast<us4*>(hi + i*4) = h;
    *reinterpret_cast<us4*>(lo + i*4) = l;
  }
}

// ===== fp32 -> bf16 hi/lo (Wo) =====
__global__ __launch_bounds__(256) void cvt_k(const float* __restrict__ src,
                                             u16* __restrict__ hi,
                                             u16* __restrict__ lo, int n) {
  int i = (blockIdx.x*256 + threadIdx.x) * 4;
  const int stride = gridDim.x * 256 * 4;
  for (; i < n; i += stride) {
    const float4 v = ld4(src + i);
    us4 h, l;
    h.x = f2bf(v.x); l.x = f2bf(v.x - bf2f(h.x));
    h.y = f2bf(v.y); l.y = f2bf(v.y - bf2f(h.y));
    h.z = f2bf(v.z); l.z = f2bf(v.z - bf2f(h.z));
    h.w = f2bf(v.w); l.w = f2bf(v.w - bf2f(h.w));
    *reinterpret_cast<us4*>(hi + i) = h;
    *reinterpret_cast<us4*>(lo + i) = l;
  }
}

// ===== fp32 wide GEMM (PreAC / Gemb) =====
struct WGP {
  const float* A; const float* W; const float* W2; const float* bias;
  const int* tgt; const float* emb;
  float* C; int ldc;
};

template<int WM>
__device__ __forceinline__ float4 ldWL(const WGP& P, int r, int k) {
  if (WM == 2) return ld4(P.W + (size_t)r * (EMBD + HID) + k);
  if (r < HID) return ld4(P.W  + (size_t)r * (2*HID) + HID + k);
  return ld4(P.W2 + (size_t)(r - HID) * (2*HID) + HID + k);
}

template<int WM>
__device__ __forceinline__ float4 ldAL(const WGP& P, int row, int k) {
  if (WM == 2) {
    const int tok = P.tgt[(row & 31) * SEQ + (row >> 5)];
    return ld4(P.emb + (size_t)tok * EMBD + k);
  }
  return ld4(P.A + (size_t)row * 1024 + k);
}

template<int WM>
__global__ __launch_bounds__(256, 2) void gemmL(WGP P) {
  constexpr int KK = (WM == 2) ? 512 : 1024;
  __shared__ float At[32*36];
  __shared__ float Wt[32*260];
  const int tid = threadIdx.x;
  const int m0 = blockIdx.x * 32;
  const int n0 = blockIdx.y * 256;
  const int lr = tid >> 3, lc = (tid & 7) << 2;
  const int tn = tid & 31, tm = tid >> 5;
  float acc[4][8];
  #pragma unroll
  for (int i = 0; i < 4; ++i)
    #pragma unroll
    for (int x = 0; x < 8; ++x) acc[i][x] = 0.f;

  float4 av = ldAL<WM>(P, m0 + lr, lc);
  float4 wv[8];
  #pragma unroll
  for (int it = 0; it < 8; ++it) wv[it] = ldWL<WM>(P, n0 + lr + it*32, lc);

  for (int k0 = 0; k0 < KK; k0 += 32) {
    float4 avn, wvn[8];
    if (k0 + 32 < KK) {
      avn = ldAL<WM>(P, m0 + lr, k0 + 32 + lc);
      #pragma unroll
      for (int it = 0; it < 8; ++it) wvn[it] = ldWL<WM>(P, n0 + lr + it*32, k0 + 32 + lc);
    }
    __syncthreads();
    At[(lc+0)*36+lr]=av.x; At[(lc+1)*36+lr]=av.y; At[(lc+2)*36+lr]=av.z; At[(lc+3)*36+lr]=av.w;
    #pragma unroll
    for (int it = 0; it < 8; ++it) {
      const int r = lr + it*32;
      Wt[(lc+0)*260+r]=wv[it].x; Wt[(lc+1)*260+r]=wv[it].y;
      Wt[(lc+2)*260+r]=wv[it].z; Wt[(lc+3)*260+r]=wv[it].w;
    }
    __syncthreads();
    #pragma unroll
    for (int kk = 0; kk < 32; ++kk) {
      const float4 a  = *reinterpret_cast<const float4*>(&At[kk*36 + tm*4]);
      const float4 w0 = *reinterpret_cast<const float4*>(&Wt[kk*260 + tn*8]);
      const float4 w1 = *reinterpret_cast<const float4*>(&Wt[kk*260 + tn*8 + 4]);
      #pragma unroll
      for (int i = 0; i < 4; ++i) {
        const float ai = (&a.x)[i];
        acc[i][0]+=ai*w0.x; acc[i][1]+=ai*w0.y; acc[i][2]+=ai*w0.z; acc[i][3]+=ai*w0.w;
        acc[i][4]+=ai*w1.x; acc[i][5]+=ai*w1.y; acc[i][6]+=ai*w1.z; acc[i][7]+=ai*w1.w;
      }
    }
    av = avn;
    #pragma unroll
    for (int it = 0; it < 8; ++it) wv[it] = wvn[it];
  }
  const int na = n0 + tn*8, ma = m0 + tm*4;
  float bb[8];
  #pragma unroll
  for (int x = 0; x < 8; ++x) {
    if (WM == 1) bb[x] = (na + x < HID) ? P.bias[na+x] : 0.f;
    else         bb[x] = 0.f;
  }
  #pragma unroll
  for (int i = 0; i < 4; ++i)
    #pragma unroll
    for (int x = 0; x < 8; ++x)
      P.C[(size_t)(ma+i)*P.ldc + na + x] = acc[i][x] + bb[x];
}

// ===== per-(b,t) log-softmax + argmax =====
__global__ __launch_bounds__(256) void lsm_k(float* __restrict__ out,
                                             float* __restrict__ words) {
  const int b = blockIdx.x;
  const int t = blockIdx.y;
  float* row = out + ((size_t)t*BATCH + b)*VOCAB;
  const int tid = threadIdx.x;
  float m = -INFINITY; int mi = 0;
  for (int v = tid; v < VOCAB; v += 256) {
    const float x = row[v];
    if (x > m) { m = x; mi = v; }
  }
  __shared__ float sm[256]; __shared__ int si[256];
  sm[tid] = m; si[tid] = mi;
  __syncthreads();
  for (int s2 = 128; s2; s2 >>= 1) {
    if (tid < s2) {
      const float om = sm[tid+s2]; const int oi = si[tid+s2];
      if (om > sm[tid] || (om == sm[tid] && oi < si[tid])) { sm[tid]=om; si[tid]=oi; }
    }
    __syncthreads();
  }
  const float mx = sm[0]; const int amax = si[0];
  float s = 0.f;
  for (int v = tid; v < VOCAB; v += 256) s += expf(row[v]-mx);
  __shared__ float ss[256];
  ss[tid] = s; __syncthreads();
  for (int s2=128; s2; s2>>=1) { if (tid < s2) ss[tid] += ss[tid+s2]; __syncthreads(); }
  const float lse = logf(ss[0]) + mx;
  for (int v = tid; v < VOCAB; v += 256) row[v] = row[v] - lse;
  if (tid == 0) words[(size_t)t*BATCH + b] = (float)amax;
}

// ===== init =====
__global__ __launch_bounds__(256) void init_k(const float* __restrict__ enc_h,
                                              const float* __restrict__ enc_c,
                                              const float* __restrict__ bih0,
                                              const float* __restrict__ bhh0,
                                              const float* __restrict__ bih1,
                                              const float* __restrict__ bhh1,
                                              float* c0, float* c1,
                                              u16* h0hi, u16* h0lo, u16* h1hi, u16* h1lo,
                                              u16* zahhi, u16* zahlo,
                                              float* bsum0, float* bsum1) {
  const int i = blockIdx.x*256 + threadIdx.x;
  if (i < BATCH*HID) {
    c0[i] = enc_c[i]; c1[i] = enc_c[BATCH*HID + i];
    const float v0 = enc_h[i];
    const u16 h0 = f2bf(v0);
    h0hi[i] = h0; h0lo[i] = f2bf(v0 - bf2f(h0));
    const float v1 = enc_h[BATCH*HID + i];
    const u16 h1 = f2bf(v1);
    h1hi[i] = h1; h1lo[i] = f2bf(v1 - bf2f(h1));
    zahhi[i] = 0; zahlo[i] = 0;
  }
  if (i < G4) {
    bsum0[i] = bih0[i] + bhh0[i];
    bsum1[i] = bih1[i] + bhh1[i];
  }
}

extern "C" void kernel_launch(void* const* d_in, const int* in_sizes, int n_in,
                              void* d_out, int out_size, void* d_ws, size_t ws_size,
                              hipStream_t stream) {
  const int*   tgt   = (const int*)d_in[0];
  const float* enc_h = (const float*)d_in[1];
  const float* enc_c = (const float*)d_in[2];
  const float* enc   = (const float*)d_in[3];
  const float* emb   = (const float*)d_in[4];
  const float* Wih0  = (const float*)d_in[5];
  const float* Whh0  = (const float*)d_in[6];
  const float* bih0  = (const float*)d_in[7];
  const float* bhh0  = (const float*)d_in[8];
  const float* Wih1  = (const float*)d_in[9];
  const float* Whh1  = (const float*)d_in[10];
  const float* bih1  = (const float*)d_in[11];
  const float* bhh1  = (const float*)d_in[12];
  const float* Wa    = (const float*)d_in[13];
  const float* ba    = (const float*)d_in[14];
  const float* va    = (const float*)d_in[15];
  const float* Wc    = (const float*)d_in[16];
  const float* bc    = (const float*)d_in[17];
  const float* Wo    = (const float*)d_in[18];
  const float* bo    = (const float*)d_in[19];

  // ---- workspace layout ----
  char* base = (char*)d_ws;
  size_t cur = 0;
  auto take = [&](size_t bytes) { char* p = base + cur; cur = (cur + bytes + 63) & ~(size_t)63; return p; };

  u16* AHhi = (u16*)take((size_t)2048*1024*2);
  u16* AHlo = (u16*)take((size_t)2048*1024*2);
  float* PreAC = (float*)take((size_t)2048*2048*4);
  float* Gemb  = (float*)take((size_t)NSTEP*BATCH*G4*4);
  float* Pq    = (float*)take((size_t)BATCH*2048*4);
  float* c0    = (float*)take(BATCH*HID*4);
  float* c1v   = (float*)take(BATCH*HID*4);
  float* bsum0 = (float*)take(G4*4);
  float* bsum1 = (float*)take(G4*4);
  u16* W0hi = (u16*)take((size_t)4096*2048*2);
  u16* W0lo = (u16*)take((size_t)4096*2048*2);
  u16* W1hi = (u16*)take((size_t)4096*2048*2);
  u16* W1lo = (u16*)take((size_t)4096*2048*2);
  u16* WAhi = (u16*)take((size_t)2048*1024*2);
  u16* WAlo = (u16*)take((size_t)2048*1024*2);
  u16* h0Ahi = (u16*)take(BATCH*HID*2);
  u16* h0Alo = (u16*)take(BATCH*HID*2);
  u16* h0Bhi = (u16*)take(BATCH*HID*2);
  u16* h0Blo = (u16*)take(BATCH*HID*2);
  u16* h1Ahi = (u16*)take(BATCH*HID*2);
  u16* h1Alo = (u16*)take(BATCH*HID*2);
  u16* h1Bhi = (u16*)take(BATCH*HID*2);
  u16* h1Blo = (u16*)take(BATCH*HID*2);
  u16* zahhi = (u16*)take(BATCH*HID*2);
  u16* zahlo = (u16*)take(BATCH*HID*2);
  const size_t loop_end = cur;                 // everything the loop needs
  // interleave mode: Wo hi/lo in fresh space after the loop pool
  u16* Wohi_i = (u16*)take((size_t)VOCAB*1024*2);
  u16* Wolo_i = (u16*)take((size_t)VOCAB*1024*2);
  const bool interleave = ws_size >= cur;
  // fallback: Wo hi/lo overlays PreAC onward (dead after loop; R11 behavior)
  u16* Wohi_f = (u16*)PreAC;
  u16* Wolo_f = Wohi_f + (size_t)VOCAB*1024;
  u16* Wohi = interleave ? Wohi_i : Wohi_f;
  u16* Wolo = interleave ? Wolo_i : Wolo_f;
  (void)loop_end;

  float* out   = (float*)d_out;
  float* words = out + (size_t)NSTEP*BATCH*VOCAB;

  init_k<<<dim3(128), 256, 0, stream>>>(enc_h, enc_c, bih0, bhh0, bih1, bhh1,
                                        c0, c1v, h0Ahi, h0Alo, h1Ahi, h1Alo,
                                        zahhi, zahlo, bsum0, bsum1);

  { // PreAC = enc @ [Wa2; Wc2]^T + [ba; 0]
    WGP p = {}; p.A = enc; p.W = Wa; p.W2 = Wc; p.bias = ba; p.C = PreAC; p.ldc = 2048;
    gemmL<1><<<dim3(64, 8), 256, 0, stream>>>(p);
  }
  { // Gemb = emb[tok] @ Wih0[:, :512]^T
    WGP p = {}; p.W = Wih0; p.tgt = tgt; p.emb = emb; p.C = Gemb; p.ldc = G4;
    gemmL<2><<<dim3(NSTEP*BATCH/32, G4/256), 256, 0, stream>>>(p);
  }
  pack_k<0><<<dim3(1024), 256, 0, stream>>>(Wih0, Whh0, W0hi, W0lo);
  pack_k<1><<<dim3(1024), 256, 0, stream>>>(Wih1, Whh1, W1hi, W1lo);
  pack_k<2><<<dim3(512), 256, 0, stream>>>(Wa, Wc, WAhi, WAlo);
  if (interleave)
    cvt_k<<<dim3(4096), 256, 0, stream>>>(Wo, Wohi, Wolo, VOCAB*1024);

  LM lm; lm.Ahi = AHhi; lm.Alo = AHlo; lm.Bhi = Wohi; lm.Blo = Wolo;
  lm.bo = bo; lm.out = out;

  int qpos = 0;
  auto next_q = [&](int t) -> int {
    if (!interleave) return 0;
    const int avail = (t < 2) ? 0 : NTILE_N * (t / 2);
    int n = avail - qpos;
    if (n > 32) n = 32;
    if (n < 0) n = 0;
    return n;
  };

  for (int t = 0; t < NSTEP; ++t) {
    const u16* ahphi = t ? (AHhi + (size_t)(t-1)*BATCH*HID) : zahhi;
    const u16* ahplo = t ? (AHlo + (size_t)(t-1)*BATCH*HID) : zahlo;
    const u16* h0phi = (t & 1) ? h0Bhi : h0Ahi;
    const u16* h0plo = (t & 1) ? h0Blo : h0Alo;
    u16* h0chi = (t & 1) ? h0Ahi : h0Bhi;
    u16* h0clo = (t & 1) ? h0Alo : h0Blo;
    const u16* h1phi = (t & 1) ? h1Bhi : h1Ahi;
    const u16* h1plo = (t & 1) ? h1Blo : h1Alo;
    u16* h1chi = (t & 1) ? h1Ahi : h1Bhi;
    u16* h1clo = (t & 1) ? h1Alo : h1Blo;

    { // L1: gates0 + cell0
      GKM p = {};
      p.Xahi = ahphi; p.Xalo = ahplo; p.Xbhi = h0phi; p.Xblo = h0plo;
      p.Whi = W0hi; p.Wlo = W0lo;
      p.bsum = bsum0; p.gembt = Gemb + (size_t)t*BATCH*G4;
      p.c = c0; p.hhi = h0chi; p.hlo = h0clo;
      p.lm = lm; p.qbase = qpos; p.qcount = next_q(t); qpos += p.qcount;
      gates_mfma_k<1><<<dim3(128 + p.qcount), 256, 0, stream>>>(p);
    }
    { // L2: gates1 + cell1
      GKM p = {};
      p.Xahi = h0chi; p.Xalo = h0clo; p.Xbhi = h1phi; p.Xblo = h1plo;
      p.Whi = W1hi; p.Wlo = W1lo;
      p.bsum = bsum1; p.gembt = nullptr;
      p.c = c1v; p.hhi = h1chi; p.hlo = h1clo;
      p.lm = lm; p.qbase = qpos; p.qcount = next_q(t); qpos += p.qcount;
      gates_mfma_k<0><<<dim3(128 + p.qcount), 256, 0, stream>>>(p);
    }
    { // L3: Pq = h1_t · [Wa1;Wc1]^T
      PKM p = {};
      p.Xhi = h1chi; p.Xlo = h1clo; p.Whi = WAhi; p.Wlo = WAlo; p.Pq = Pq;
      p.lm = lm; p.qbase = qpos; p.qcount = next_q(t); qpos += p.qcount;
      proj_mfma_k<<<dim3(64 + p.qcount), 256, 0, stream>>>(p);
    }
    { // L4: attention -> AH[t]
      AKM p = {};
      p.Pq = Pq; p.PreAC = PreAC; p.va = va; p.bc = bc;
      p.AHthi = AHhi + (size_t)t*BATCH*HID;
      p.AHtlo = AHlo + (size_t)t*BATCH*HID;
      p.lm = lm; p.qbase = qpos; p.qcount = next_q(t); qpos += p.qcount;
      attn_k<<<dim3(32 + p.qcount), 256, 0, stream>>>(p);
    }
  }

  // epilogue
  if (!interleave)
    cvt_k<<<dim3(4096), 256, 0, stream>>>(Wo, Wohi, Wolo, VOCAB*1024);
  if (qpos < NTILES)
    logits_tiles_k<<<dim3(NTILES - qpos), 256, 0, stream>>>(lm, qpos);
  lsm_k<<<dim3(BATCH, NSTEP), 256, 0, stream>>>(out, words);
}

// Round 13
// 6062.081 us; speedup vs baseline: 2.0781x; 2.0781x over previous
//
#include <hip/hip_runtime.h>
#include <math.h>

#define VOCAB 32000
#define EMBD  512
#define HID   1024
#define BATCH 32
#define SEQ   64
#define TENC  64
#define NSTEP 63
#define G4    4096

typedef __attribute__((ext_vector_type(8))) short short8;
typedef __attribute__((ext_vector_type(4))) float f32x4;
typedef __attribute__((ext_vector_type(4))) unsigned short us4;
typedef unsigned short u16;

__device__ __forceinline__ float4 ld4(const float* p) {
  return *reinterpret_cast<const float4*>(p);
}
__device__ __forceinline__ u16 f2bf(float x) {
  unsigned u = __float_as_uint(x);
  return (u16)((u + 0x7fffu + ((u >> 16) & 1u)) >> 16);
}
__device__ __forceinline__ float bf2f(u16 h) {
  return __uint_as_float(((unsigned)h) << 16);
}

// ===== MFMA 32x32 tile core (R11, validated) =====
template<int MODE>
__device__ __forceinline__ void mfma32(
    const u16* __restrict__ Xahi, const u16* __restrict__ Xalo,
    const u16* __restrict__ Xbhi, const u16* __restrict__ Xblo,
    const u16* __restrict__ Whi,  const u16* __restrict__ Wlo,
    int nt, float* res)
{
  const int tid = threadIdx.x;
  const int w = tid >> 6, l = tid & 63;
  const int c = l & 15, koct = l >> 4;
  constexpr int K   = (MODE == 0) ? 2048 : 1024;
  constexpr int WS  = (MODE == 0) ? 2048 : 1024;
  constexpr int SPW = K / 32 / 4;
  const int r0 = c, r1 = 16 + c;
  const int wr0 = (MODE == 0) ? ((r0 >> 3)*1024 + nt*8 + (r0 & 7)) : (nt*32 + r0);
  const int wr1 = (MODE == 0) ? ((r1 >> 3)*1024 + nt*8 + (r1 & 7)) : (nt*32 + r1);
  const u16* bh0 = Whi + (size_t)wr0 * WS;
  const u16* bh1 = Whi + (size_t)wr1 * WS;
  const u16* bl0 = Wlo + (size_t)wr0 * WS;
  const u16* bl1 = Wlo + (size_t)wr1 * WS;

  auto ldA = [&](int m, int kg, int lo) -> short8 {
    const u16* base;
    if (MODE == 0 && kg >= 1024) base = lo ? Xblo : Xbhi;
    else                         base = lo ? Xalo : Xahi;
    const int b = m*16 + c;
    return *reinterpret_cast<const short8*>(base + b*1024 + (kg & 1023));
  };

  f32x4 acc[2][2];
  #pragma unroll
  for (int m = 0; m < 2; ++m)
    #pragma unroll
    for (int n = 0; n < 2; ++n) acc[m][n] = (f32x4){0.f,0.f,0.f,0.f};

  const int s0 = w * SPW;
  short8 Ah[2], Al[2], Bh[2], Bl[2];
  {
    const int kg = s0*32 + koct*8;
    Ah[0]=ldA(0,kg,0); Ah[1]=ldA(1,kg,0); Al[0]=ldA(0,kg,1); Al[1]=ldA(1,kg,1);
    Bh[0]=*reinterpret_cast<const short8*>(bh0+kg);
    Bh[1]=*reinterpret_cast<const short8*>(bh1+kg);
    Bl[0]=*reinterpret_cast<const short8*>(bl0+kg);
    Bl[1]=*reinterpret_cast<const short8*>(bl1+kg);
  }
  for (int s = s0; s < s0 + SPW; ++s) {
    short8 nAh[2], nAl[2], nBh[2], nBl[2];
    if (s + 1 < s0 + SPW) {
      const int kg = (s+1)*32 + koct*8;
      nAh[0]=ldA(0,kg,0); nAh[1]=ldA(1,kg,0); nAl[0]=ldA(0,kg,1); nAl[1]=ldA(1,kg,1);
      nBh[0]=*reinterpret_cast<const short8*>(bh0+kg);
      nBh[1]=*reinterpret_cast<const short8*>(bh1+kg);
      nBl[0]=*reinterpret_cast<const short8*>(bl0+kg);
      nBl[1]=*reinterpret_cast<const short8*>(bl1+kg);
    }
    #pragma unroll
    for (int n = 0; n < 2; ++n)
      #pragma unroll
      for (int m = 0; m < 2; ++m) {
        acc[m][n] = __builtin_amdgcn_mfma_f32_16x16x32_bf16(Ah[m], Bh[n], acc[m][n], 0, 0, 0);
        acc[m][n] = __builtin_amdgcn_mfma_f32_16x16x32_bf16(Ah[m], Bl[n], acc[m][n], 0, 0, 0);
        acc[m][n] = __builtin_amdgcn_mfma_f32_16x16x32_bf16(Al[m], Bh[n], acc[m][n], 0, 0, 0);
      }
    #pragma unroll
    for (int i = 0; i < 2; ++i) { Ah[i]=nAh[i]; Al[i]=nAl[i]; Bh[i]=nBh[i]; Bl[i]=nBl[i]; }
  }
  #pragma unroll
  for (int m = 0; m < 2; ++m)
    #pragma unroll
    for (int n = 0; n < 2; ++n)
      #pragma unroll
      for (int r = 0; r < 4; ++r) {
        const int b = m*16 + koct*4 + r;
        const int rr = n*16 + c;
        res[w*1056 + b*33 + rr] = acc[m][n][r];
      }
}

// ===== L1/L2: gates + cell (R11) =====
struct GKM {
  const u16 *Xahi, *Xalo, *Xbhi, *Xblo;
  const u16 *Whi, *Wlo;
  const float* bsum; const float* gembt;
  float* c; u16 *hhi; u16 *hlo;
};

template<int HASGEMB>
__global__ __launch_bounds__(256) void gates_mfma_k(GKM P) {
  __shared__ float res[4*1056];
  mfma32<0>(P.Xahi, P.Xalo, P.Xbhi, P.Xblo, P.Whi, P.Wlo, blockIdx.x, res);
  __syncthreads();
  const int tid = threadIdx.x;
  const int b = tid >> 3, j = tid & 7;
  const int n = blockIdx.x*8 + j;
  float g4[4];
  #pragma unroll
  for (int g = 0; g < 4; ++g) {
    const int r = g*8 + j;
    float s = P.bsum[g*1024 + n]
            + res[b*33+r] + res[1056 + b*33+r] + res[2112 + b*33+r] + res[3168 + b*33+r];
    if (HASGEMB) s += P.gembt[(size_t)b*G4 + g*1024 + n];
    g4[g] = s;
  }
  const float si = 1.f/(1.f+expf(-g4[0]));
  const float sf = 1.f/(1.f+expf(-g4[1]));
  const float so = 1.f/(1.f+expf(-g4[3]));
  const int i = b*HID + n;
  const float cn = sf*P.c[i] + si*tanhf(g4[2]);
  P.c[i] = cn;
  const float h = so*tanhf(cn);
  const u16 hh = f2bf(h);
  P.hhi[i] = hh;
  P.hlo[i] = f2bf(h - bf2f(hh));
}

// ===== L3: proj (R11) =====
struct PKM {
  const u16 *Xhi, *Xlo; const u16 *Whi, *Wlo; float* Pq;
};

__global__ __launch_bounds__(256) void proj_mfma_k(PKM P) {
  __shared__ float res[4*1056];
  mfma32<1>(P.Xhi, P.Xlo, nullptr, nullptr, P.Whi, P.Wlo, blockIdx.x, res);
  __syncthreads();
  const int tid = threadIdx.x;
  #pragma unroll
  for (int q = 0; q < 4; ++q) {
    const int o = q*256 + tid;
    const int b = o >> 5, r = o & 31;
    const float s = res[b*33+r] + res[1056 + b*33+r]
                  + res[2112 + b*33+r] + res[3168 + b*33+r];
    P.Pq[(size_t)b*2048 + blockIdx.x*32 + r] = s;
  }
}

// ===== L4: attention (R11, 1024 thr) =====
struct AKM {
  const float* Pq; const float* PreAC; const float* va; const float* bc;
  u16* AHthi; u16* AHtlo;
};

__global__ __launch_bounds__(1024) void attn_k(AKM P) {
  __shared__ float QS[HID];
  __shared__ float sw[TENC];
  __shared__ float W64[TENC];
  const int b = blockIdx.x;
  const int tid = threadIdx.x;
  QS[tid] = P.Pq[(size_t)b*2048 + tid];
  __syncthreads();
  const int lane = tid & 63, wid = tid >> 6;    // 16 waves
  float vreg[16];
  #pragma unroll
  for (int i2 = 0; i2 < 16; ++i2) vreg[i2] = P.va[lane + 64*i2];
  #pragma unroll
  for (int j = 0; j < 4; ++j) {
    const int te = wid*4 + j;
    const float* pr = P.PreAC + ((size_t)te*BATCH + b)*2048;
    float s = 0.f;
    #pragma unroll
    for (int i2 = 0; i2 < 16; ++i2) {
      const int idx = lane + 64*i2;
      s += vreg[i2] * tanhf(QS[idx] + pr[idx]);
    }
    #pragma unroll
    for (int off = 32; off; off >>= 1) s += __shfl_xor(s, off);
    if (lane == 0) sw[te] = s;
  }
  __syncthreads();
  if (tid < TENC) {
    const float v = sw[tid];
    float mx = v;
    #pragma unroll
    for (int off = 32; off; off >>= 1) mx = fmaxf(mx, __shfl_xor(mx, off));
    const float e = expf(v - mx);
    float sum = e;
    #pragma unroll
    for (int off = 32; off; off >>= 1) sum += __shfl_xor(sum, off);
    W64[tid] = e / sum;
  }
  __syncthreads();
  const int hh = tid;
  float acc = 0.f;
  #pragma unroll 8
  for (int te = 0; te < TENC; ++te)
    acc += W64[te] * P.PreAC[((size_t)te*BATCH + b)*2048 + HID + hh];
  const float hc = P.Pq[(size_t)b*2048 + HID + hh] + P.bc[hh];
  const float ah = tanhf(acc + hc);
  const u16 ahh = f2bf(ah);
  P.AHthi[(size_t)b*HID + hh] = ahh;
  P.AHtlo[(size_t)b*HID + hh] = f2bf(ah - bf2f(ahh));
}

// ===== generalized split-bf16 MFMA tile: out[64m x 128n] = A·B^T (+bias) =====
// NC = K/32. AMODE 0: A row i at Ahi+i*K. AMODE 1: A row i gathered from emb
// via tgt (row = t*32+b), stride K.
struct TM {
  const u16 *Ahi, *Alo, *Bhi, *Blo;
  const int* tgt; const float* bias;
  float* out; int ldc, M, ntile_n;
};

template<int NC, int AMODE>
__global__ __launch_bounds__(256) void tile_k(TM P) {
  __shared__ float smemf[6144];
  u16* sA = (u16*)smemf;          // [2][4][64][8]
  u16* sB = sA + 4096;            // [2][4][128][8]
  constexpr int K = NC * 32;
  const int tile = blockIdx.x;
  const int mi = tile / P.ntile_n, ni = tile % P.ntile_n;
  const int m0 = mi * 64, n0 = ni * 128;
  const int tid = threadIdx.x;
  const int w = tid >> 6, l = tid & 63;
  const int mb = (w & 1) * 32, nb = (w >> 1) * 64;
  f32x4 acc[2][4];
  #pragma unroll
  for (int mt = 0; mt < 2; ++mt)
    #pragma unroll
    for (int nt = 0; nt < 4; ++nt) acc[mt][nt] = (f32x4){0.f,0.f,0.f,0.f};

  const int arow = tid >> 2, akg = tid & 3;
  const int brow = tid >> 1, bkg = (tid & 1) * 2;
  size_t arbase;
  if (AMODE == 1) {
    const int row = m0 + arow;
    const int tok = P.tgt[(row & 31)*SEQ + (row >> 5)];
    arbase = (size_t)tok * K;
  } else {
    arbase = (size_t)(m0 + arow) * K;
  }
  const size_t brbase = (size_t)(n0 + brow) * K;

  short8 pah, pal, pbh0, pbh1, pbl0, pbl1;
  {
    const size_t ao = arbase + akg*8;
    const size_t bo0 = brbase + bkg*8;
    pah  = *reinterpret_cast<const short8*>(P.Ahi + ao);
    pal  = *reinterpret_cast<const short8*>(P.Alo + ao);
    pbh0 = *reinterpret_cast<const short8*>(P.Bhi + bo0);
    pbh1 = *reinterpret_cast<const short8*>(P.Bhi + bo0 + 8);
    pbl0 = *reinterpret_cast<const short8*>(P.Blo + bo0);
    pbl1 = *reinterpret_cast<const short8*>(P.Blo + bo0 + 8);
  }
  for (int kc = 0; kc < NC; ++kc) {
    __syncthreads();
    *reinterpret_cast<short8*>(sA + ((0*4 + akg)*64 + arow)*8) = pah;
    *reinterpret_cast<short8*>(sA + ((1*4 + akg)*64 + arow)*8) = pal;
    *reinterpret_cast<short8*>(sB + ((0*4 + bkg  )*128 + brow)*8) = pbh0;
    *reinterpret_cast<short8*>(sB + ((0*4 + bkg+1)*128 + brow)*8) = pbh1;
    *reinterpret_cast<short8*>(sB + ((1*4 + bkg  )*128 + brow)*8) = pbl0;
    *reinterpret_cast<short8*>(sB + ((1*4 + bkg+1)*128 + brow)*8) = pbl1;
    __syncthreads();
    if (kc + 1 < NC) {
      const size_t ao = arbase + (kc+1)*32 + akg*8;
      const size_t bo0 = brbase + (kc+1)*32 + bkg*8;
      pah  = *reinterpret_cast<const short8*>(P.Ahi + ao);
      pal  = *reinterpret_cast<const short8*>(P.Alo + ao);
      pbh0 = *reinterpret_cast<const short8*>(P.Bhi + bo0);
      pbh1 = *reinterpret_cast<const short8*>(P.Bhi + bo0 + 8);
      pbl0 = *reinterpret_cast<const short8*>(P.Blo + bo0);
      pbl1 = *reinterpret_cast<const short8*>(P.Blo + bo0 + 8);
    }
    const int kg = l >> 4, rr = l & 15;
    short8 ah[2], al[2];
    #pragma unroll
    for (int mt = 0; mt < 2; ++mt) {
      ah[mt] = *reinterpret_cast<const short8*>(sA + ((0*4 + kg)*64 + mb + mt*16 + rr)*8);
      al[mt] = *reinterpret_cast<const short8*>(sA + ((1*4 + kg)*64 + mb + mt*16 + rr)*8);
    }
    #pragma unroll
    for (int nt = 0; nt < 4; ++nt) {
      const short8 bh = *reinterpret_cast<const short8*>(sB + ((0*4 + kg)*128 + nb + nt*16 + rr)*8);
      const short8 bl = *reinterpret_cast<const short8*>(sB + ((1*4 + kg)*128 + nb + nt*16 + rr)*8);
      #pragma unroll
      for (int mt = 0; mt < 2; ++mt) {
        acc[mt][nt] = __builtin_amdgcn_mfma_f32_16x16x32_bf16(ah[mt], bh, acc[mt][nt], 0, 0, 0);
        acc[mt][nt] = __builtin_amdgcn_mfma_f32_16x16x32_bf16(ah[mt], bl, acc[mt][nt], 0, 0, 0);
        acc[mt][nt] = __builtin_amdgcn_mfma_f32_16x16x32_bf16(al[mt], bh, acc[mt][nt], 0, 0, 0);
      }
    }
  }
  #pragma unroll
  for (int mt = 0; mt < 2; ++mt) {
    #pragma unroll
    for (int nt = 0; nt < 4; ++nt) {
      #pragma unroll
      for (int r = 0; r < 4; ++r) {
        const int row = m0 + mb + mt*16 + (l >> 4)*4 + r;
        const int col = n0 + nb + nt*16 + (l & 15);
        if (row < P.M) {
          const float bb = P.bias ? P.bias[col] : 0.f;
          P.out[(size_t)row*P.ldc + col] = acc[mt][nt][r] + bb;
        }
      }
    }
  }
}

// ===== weight pack + hi/lo split =====
// 0: [4096][2048] <- [Wih0[:,512:1536] | Whh0]
// 1: [4096][2048] <- [Wih1 | Whh1]
// 2: [2048][1024] <- [Wa1; Wc1]   (cols 0..1023, stride 2048)
// 3: [2048][1024] <- [Wa2; Wc2]   (cols 1024..2047, stride 2048)
// 4: [4096][512]  <- Wih0[:, 0:512] (stride 1536)
template<int MODE>
__global__ __launch_bounds__(256) void pack_k(const float* __restrict__ A,
                                              const float* __restrict__ B,
                                              u16* __restrict__ hi, u16* __restrict__ lo) {
  constexpr int ROWS = (MODE == 2 || MODE == 3) ? 2048 : 4096;
  constexpr int K    = (MODE == 2 || MODE == 3) ? 1024 : (MODE == 4 ? 512 : 2048);
  const size_t total = (size_t)ROWS * (K/4);
  for (size_t i = (size_t)blockIdx.x*256 + threadIdx.x; i < total;
       i += (size_t)gridDim.x*256) {
    const int row = (int)(i / (K/4));
    const int k = (int)(i % (K/4)) * 4;
    float4 v;
    if (MODE == 0) v = (k < 1024) ? ld4(A + (size_t)row*1536 + 512 + k)
                                  : ld4(B + (size_t)row*1024 + (k - 1024));
    else if (MODE == 1) v = (k < 1024) ? ld4(A + (size_t)row*1024 + k)
                                       : ld4(B + (size_t)row*1024 + (k - 1024));
    else if (MODE == 2) v = (row < 1024) ? ld4(A + (size_t)row*2048 + k)
                                         : ld4(B + (size_t)(row - 1024)*2048 + k);
    else if (MODE == 3) v = (row < 1024) ? ld4(A + (size_t)row*2048 + 1024 + k)
                                         : ld4(B + (size_t)(row - 1024)*2048 + 1024 + k);
    else v = ld4(A + (size_t)row*1536 + k);
    us4 h, l;
    h.x = f2bf(v.x); l.x = f2bf(v.x - bf2f(h.x));
    h.y = f2bf(v.y); l.y = f2bf(v.y - bf2f(h.y));
    h.z = f2bf(v.z); l.z = f2bf(v.z - bf2f(h.z));
    h.w = f2bf(v.w); l.w = f2bf(v.w - bf2f(h.w));
    *reinterpret_cast<us4*>(hi + i*4) = h;
    *reinterpret_cast<us4*>(lo + i*4) = l;
  }
}

// ===== fp32 -> bf16 hi/lo =====
__global__ __launch_bounds__(256) void cvt_k(const float* __restrict__ src,
                                             u16* __restrict__ hi,
                                             u16* __restrict__ lo, int n) {
  int i = (blockIdx.x*256 + threadIdx.x) * 4;
  const int stride = gridDim.x * 256 * 4;
  for (; i < n; i += stride) {
    const float4 v = ld4(src + i);
    us4 h, l;
    h.x = f2bf(v.x); l.x = f2bf(v.x - bf2f(h.x));
    h.y = f2bf(v.y); l.y = f2bf(v.y - bf2f(h.y));
    h.z = f2bf(v.z); l.z = f2bf(v.z - bf2f(h.z));
    h.w = f2bf(v.w); l.w = f2bf(v.w - bf2f(h.w));
    *reinterpret_cast<us4*>(hi + i) = h;
    *reinterpret_cast<us4*>(lo + i) = l;
  }
}

// ===== fp32 wide GEMM (fallback PreAC / Gemb only) =====
struct WGP {
  const float* A; const float* W; const float* W2; const float* bias;
  const int* tgt; const float* emb;
  float* C; int ldc;
};

template<int WM>
__device__ __forceinline__ float4 ldWL(const WGP& P, int r, int k) {
  if (WM == 2) return ld4(P.W + (size_t)r * (EMBD + HID) + k);
  if (r < HID) return ld4(P.W  + (size_t)r * (2*HID) + HID + k);
  return ld4(P.W2 + (size_t)(r - HID) * (2*HID) + HID + k);
}

template<int WM>
__device__ __forceinline__ float4 ldAL(const WGP& P, int row, int k) {
  if (WM == 2) {
    const int tok = P.tgt[(row & 31) * SEQ + (row >> 5)];
    return ld4(P.emb + (size_t)tok * EMBD + k);
  }
  return ld4(P.A + (size_t)row * 1024 + k);
}

template<int WM>
__global__ __launch_bounds__(256, 2) void gemmL(WGP P) {
  constexpr int KK = (WM == 2) ? 512 : 1024;
  __shared__ float At[32*36];
  __shared__ float Wt[32*260];
  const int tid = threadIdx.x;
  const int m0 = blockIdx.x * 32;
  const int n0 = blockIdx.y * 256;
  const int lr = tid >> 3, lc = (tid & 7) << 2;
  const int tn = tid & 31, tm = tid >> 5;
  float acc[4][8];
  #pragma unroll
  for (int i = 0; i < 4; ++i)
    #pragma unroll
    for (int x = 0; x < 8; ++x) acc[i][x] = 0.f;

  float4 av = ldAL<WM>(P, m0 + lr, lc);
  float4 wv[8];
  #pragma unroll
  for (int it = 0; it < 8; ++it) wv[it] = ldWL<WM>(P, n0 + lr + it*32, lc);

  for (int k0 = 0; k0 < KK; k0 += 32) {
    float4 avn, wvn[8];
    if (k0 + 32 < KK) {
      avn = ldAL<WM>(P, m0 + lr, k0 + 32 + lc);
      #pragma unroll
      for (int it = 0; it < 8; ++it) wvn[it] = ldWL<WM>(P, n0 + lr + it*32, k0 + 32 + lc);
    }
    __syncthreads();
    At[(lc+0)*36+lr]=av.x; At[(lc+1)*36+lr]=av.y; At[(lc+2)*36+lr]=av.z; At[(lc+3)*36+lr]=av.w;
    #pragma unroll
    for (int it = 0; it < 8; ++it) {
      const int r = lr + it*32;
      Wt[(lc+0)*260+r]=wv[it].x; Wt[(lc+1)*260+r]=wv[it].y;
      Wt[(lc+2)*260+r]=wv[it].z; Wt[(lc+3)*260+r]=wv[it].w;
    }
    __syncthreads();
    #pragma unroll
    for (int kk = 0; kk < 32; ++kk) {
      const float4 a  = *reinterpret_cast<const float4*>(&At[kk*36 + tm*4]);
      const float4 w0 = *reinterpret_cast<const float4*>(&Wt[kk*260 + tn*8]);
      const float4 w1 = *reinterpret_cast<const float4*>(&Wt[kk*260 + tn*8 + 4]);
      #pragma unroll
      for (int i = 0; i < 4; ++i) {
        const float ai = (&a.x)[i];
        acc[i][0]+=ai*w0.x; acc[i][1]+=ai*w0.y; acc[i][2]+=ai*w0.z; acc[i][3]+=ai*w0.w;
        acc[i][4]+=ai*w1.x; acc[i][5]+=ai*w1.y; acc[i][6]+=ai*w1.z; acc[i][7]+=ai*w1.w;
      }
    }
    av = avn;
    #pragma unroll
    for (int it = 0; it < 8; ++it) wv[it] = wvn[it];
  }
  const int na = n0 + tn*8, ma = m0 + tm*4;
  float bb[8];
  #pragma unroll
  for (int x = 0; x < 8; ++x) {
    if (WM == 1) bb[x] = (na + x < HID) ? P.bias[na+x] : 0.f;
    else         bb[x] = 0.f;
  }
  #pragma unroll
  for (int i = 0; i < 4; ++i)
    #pragma unroll
    for (int x = 0; x < 8; ++x)
      P.C[(size_t)(ma+i)*P.ldc + na + x] = acc[i][x] + bb[x];
}

// ===== per-(b,t) log-softmax + argmax, online single-pass max+sum =====
__global__ __launch_bounds__(512) void lsm_k(float* __restrict__ out,
                                             float* __restrict__ words) {
  const int b = blockIdx.x;
  const int t = blockIdx.y;
  float* row = out + ((size_t)t*BATCH + b)*VOCAB;
  const int tid = threadIdx.x;
  float m = -INFINITY, s = 0.f; int mi = 0;
  for (int v = tid; v < VOCAB; v += 512) {
    const float x = row[v];
    if (x > m) { s = s * expf(m - x) + 1.f; m = x; mi = v; }
    else s += expf(x - m);
  }
  __shared__ float sm[512]; __shared__ float sv[512]; __shared__ int si[512];
  sm[tid] = m; sv[tid] = s; si[tid] = mi;
  __syncthreads();
  for (int st = 256; st; st >>= 1) {
    if (tid < st) {
      const float om = sm[tid+st], os = sv[tid+st]; const int oi = si[tid+st];
      if (om > sm[tid]) {
        sv[tid] = os + sv[tid] * expf(sm[tid] - om);
        sm[tid] = om; si[tid] = oi;
      } else if (om == sm[tid]) {
        sv[tid] += os;
        if (oi < si[tid]) si[tid] = oi;
      } else {
        sv[tid] += os * expf(om - sm[tid]);
      }
    }
    __syncthreads();
  }
  const float lse = logf(sv[0]) + sm[0];
  const int amax = si[0];
  for (int v = tid; v < VOCAB; v += 512) row[v] = row[v] - lse;
  if (tid == 0) words[(size_t)t*BATCH + b] = (float)amax;
}

// ===== init =====
__global__ __launch_bounds__(256) void init_k(const float* __restrict__ enc_h,
                                              const float* __restrict__ enc_c,
                                              const float* __restrict__ bih0,
                                              const float* __restrict__ bhh0,
                                              const float* __restrict__ bih1,
                                              const float* __restrict__ bhh1,
                                              const float* __restrict__ ba,
                                              float* c0, float* c1,
                                              u16* h0hi, u16* h0lo, u16* h1hi, u16* h1lo,
                                              u16* zahhi, u16* zahlo,
                                              float* bsum0, float* bsum1,
                                              float* bias2048) {
  const int i = blockIdx.x*256 + threadIdx.x;
  if (i < BATCH*HID) {
    c0[i] = enc_c[i]; c1[i] = enc_c[BATCH*HID + i];
    const float v0 = enc_h[i];
    const u16 h0 = f2bf(v0);
    h0hi[i] = h0; h0lo[i] = f2bf(v0 - bf2f(h0));
    const float v1 = enc_h[BATCH*HID + i];
    const u16 h1 = f2bf(v1);
    h1hi[i] = h1; h1lo[i] = f2bf(v1 - bf2f(h1));
    zahhi[i] = 0; zahlo[i] = 0;
  }
  if (i < G4) {
    bsum0[i] = bih0[i] + bhh0[i];
    bsum1[i] = bih1[i] + bhh1[i];
  }
  if (i < 2048) bias2048[i] = (i < HID) ? ba[i] : 0.f;
}

extern "C" void kernel_launch(void* const* d_in, const int* in_sizes, int n_in,
                              void* d_out, int out_size, void* d_ws, size_t ws_size,
                              hipStream_t stream) {
  const int*   tgt   = (const int*)d_in[0];
  const float* enc_h = (const float*)d_in[1];
  const float* enc_c = (const float*)d_in[2];
  const float* enc   = (const float*)d_in[3];
  const float* emb   = (const float*)d_in[4];
  const float* Wih0  = (const float*)d_in[5];
  const float* Whh0  = (const float*)d_in[6];
  const float* bih0  = (const float*)d_in[7];
  const float* bhh0  = (const float*)d_in[8];
  const float* Wih1  = (const float*)d_in[9];
  const float* Whh1  = (const float*)d_in[10];
  const float* bih1  = (const float*)d_in[11];
  const float* bhh1  = (const float*)d_in[12];
  const float* Wa    = (const float*)d_in[13];
  const float* ba    = (const float*)d_in[14];
  const float* va    = (const float*)d_in[15];
  const float* Wc    = (const float*)d_in[16];
  const float* bc    = (const float*)d_in[17];
  const float* Wo    = (const float*)d_in[18];
  const float* bo    = (const float*)d_in[19];

  // ---- workspace layout ----
  char* base = (char*)d_ws;
  size_t cur = 0;
  auto take = [&](size_t bytes) { char* p = base + cur; cur = (cur + bytes + 63) & ~(size_t)63; return p; };

  u16* AHhi = (u16*)take((size_t)2048*1024*2);
  u16* AHlo = (u16*)take((size_t)2048*1024*2);
  float* PreAC = (float*)take((size_t)2048*2048*4);
  float* Gemb  = (float*)take((size_t)NSTEP*BATCH*G4*4);
  float* Pq    = (float*)take((size_t)BATCH*2048*4);
  float* c0    = (float*)take(BATCH*HID*4);
  float* c1v   = (float*)take(BATCH*HID*4);
  float* bsum0 = (float*)take(G4*4);
  float* bsum1 = (float*)take(G4*4);
  float* bias2048 = (float*)take(2048*4);
  u16* W0hi = (u16*)take((size_t)4096*2048*2);
  u16* W0lo = (u16*)take((size_t)4096*2048*2);
  u16* W1hi = (u16*)take((size_t)4096*2048*2);
  u16* W1lo = (u16*)take((size_t)4096*2048*2);
  u16* WAhi = (u16*)take((size_t)2048*1024*2);
  u16* WAlo = (u16*)take((size_t)2048*1024*2);
  u16* h0Ahi = (u16*)take(BATCH*HID*2);
  u16* h0Alo = (u16*)take(BATCH*HID*2);
  u16* h0Bhi = (u16*)take(BATCH*HID*2);
  u16* h0Blo = (u16*)take(BATCH*HID*2);
  u16* h1Ahi = (u16*)take(BATCH*HID*2);
  u16* h1Alo = (u16*)take(BATCH*HID*2);
  u16* h1Bhi = (u16*)take(BATCH*HID*2);
  u16* h1Blo = (u16*)take(BATCH*HID*2);
  u16* zahhi = (u16*)take(BATCH*HID*2);
  u16* zahlo = (u16*)take(BATCH*HID*2);
  // shared scratch S: pre-loop input splits, then Wo hi/lo post-loop
  char* S = take((size_t)VOCAB*1024*2*2);          // 131 MB
  const bool fast = ws_size >= cur;

  // pre-loop split views in S (lifetimes end before loop)
  u16* enchi = (u16*)S;
  u16* enclo = enchi + (size_t)2048*1024;
  u16* embhi = enclo + (size_t)2048*1024;
  u16* emblo = embhi + (size_t)VOCAB*EMBD;
  u16* WAChi = emblo + (size_t)VOCAB*EMBD;
  u16* WAClo = WAChi + (size_t)2048*1024;
  u16* W0ehi = WAClo + (size_t)2048*1024;
  u16* W0elo = W0ehi + (size_t)4096*512;
  // post-loop views in S (fast) or overlay on PreAC (fallback, R11 behavior)
  u16* Wohi = fast ? (u16*)S : (u16*)PreAC;
  u16* Wolo = Wohi + (size_t)VOCAB*1024;

  float* out   = (float*)d_out;
  float* words = out + (size_t)NSTEP*BATCH*VOCAB;

  init_k<<<dim3(128), 256, 0, stream>>>(enc_h, enc_c, bih0, bhh0, bih1, bhh1, ba,
                                        c0, c1v, h0Ahi, h0Alo, h1Ahi, h1Alo,
                                        zahhi, zahlo, bsum0, bsum1, bias2048);

  if (fast) {
    cvt_k<<<dim3(512), 256, 0, stream>>>(enc, enchi, enclo, 2048*1024);
    cvt_k<<<dim3(4096), 256, 0, stream>>>(emb, embhi, emblo, VOCAB*EMBD);
    pack_k<3><<<dim3(512), 256, 0, stream>>>(Wa, Wc, WAChi, WAClo);
    pack_k<4><<<dim3(512), 256, 0, stream>>>(Wih0, nullptr, W0ehi, W0elo);
    { // PreAC = enc @ [Wa2;Wc2]^T + [ba;0]   (MFMA tiles)
      TM p; p.Ahi = enchi; p.Alo = enclo; p.Bhi = WAChi; p.Blo = WAClo;
      p.tgt = nullptr; p.bias = bias2048; p.out = PreAC;
      p.ldc = 2048; p.M = 2048; p.ntile_n = 16;
      tile_k<32,0><<<dim3(512), 256, 0, stream>>>(p);
    }
    { // Gemb = emb[tok] @ Wih0[:, :512]^T   (MFMA tiles, gathered A)
      TM p; p.Ahi = embhi; p.Alo = emblo; p.Bhi = W0ehi; p.Blo = W0elo;
      p.tgt = tgt; p.bias = nullptr; p.out = Gemb;
      p.ldc = G4; p.M = NSTEP*BATCH; p.ntile_n = 32;
      tile_k<16,1><<<dim3(1024), 256, 0, stream>>>(p);
    }
  } else {
    { WGP p = {}; p.A = enc; p.W = Wa; p.W2 = Wc; p.bias = ba; p.C = PreAC; p.ldc = 2048;
      gemmL<1><<<dim3(64, 8), 256, 0, stream>>>(p); }
    { WGP p = {}; p.W = Wih0; p.tgt = tgt; p.emb = emb; p.C = Gemb; p.ldc = G4;
      gemmL<2><<<dim3(NSTEP*BATCH/32, G4/256), 256, 0, stream>>>(p); }
  }
  pack_k<0><<<dim3(1024), 256, 0, stream>>>(Wih0, Whh0, W0hi, W0lo);
  pack_k<1><<<dim3(1024), 256, 0, stream>>>(Wih1, Whh1, W1hi, W1lo);
  pack_k<2><<<dim3(512), 256, 0, stream>>>(Wa, Wc, WAhi, WAlo);

  for (int t = 0; t < NSTEP; ++t) {
    const u16* ahphi = t ? (AHhi + (size_t)(t-1)*BATCH*HID) : zahhi;
    const u16* ahplo = t ? (AHlo + (size_t)(t-1)*BATCH*HID) : zahlo;
    const u16* h0phi = (t & 1) ? h0Bhi : h0Ahi;
    const u16* h0plo = (t & 1) ? h0Blo : h0Alo;
    u16* h0chi = (t & 1) ? h0Ahi : h0Bhi;
    u16* h0clo = (t & 1) ? h0Alo : h0Blo;
    const u16* h1phi = (t & 1) ? h1Bhi : h1Ahi;
    const u16* h1plo = (t & 1) ? h1Blo : h1Alo;
    u16* h1chi = (t & 1) ? h1Ahi : h1Bhi;
    u16* h1clo = (t & 1) ? h1Alo : h1Blo;

    { // L1: gates0 + cell0
      GKM p = {};
      p.Xahi = ahphi; p.Xalo = ahplo; p.Xbhi = h0phi; p.Xblo = h0plo;
      p.Whi = W0hi; p.Wlo = W0lo;
      p.bsum = bsum0; p.gembt = Gemb + (size_t)t*BATCH*G4;
      p.c = c0; p.hhi = h0chi; p.hlo = h0clo;
      gates_mfma_k<1><<<dim3(128), 256, 0, stream>>>(p);
    }
    { // L2: gates1 + cell1
      GKM p = {};
      p.Xahi = h0chi; p.Xalo = h0clo; p.Xbhi = h1phi; p.Xblo = h1plo;
      p.Whi = W1hi; p.Wlo = W1lo;
      p.bsum = bsum1; p.gembt = nullptr;
      p.c = c1v; p.hhi = h1chi; p.hlo = h1clo;
      gates_mfma_k<0><<<dim3(128), 256, 0, stream>>>(p);
    }
    { // L3: Pq = h1_t · [Wa1;Wc1]^T
      PKM p; p.Xhi = h1chi; p.Xlo = h1clo; p.Whi = WAhi; p.Wlo = WAlo; p.Pq = Pq;
      proj_mfma_k<<<dim3(64), 256, 0, stream>>>(p);
    }
    { // L4: attention -> AH[t] (bf16 hi/lo)
      AKM p; p.Pq = Pq; p.PreAC = PreAC; p.va = va; p.bc = bc;
      p.AHthi = AHhi + (size_t)t*BATCH*HID;
      p.AHtlo = AHlo + (size_t)t*BATCH*HID;
      attn_k<<<dim3(BATCH), 1024, 0, stream>>>(p);
    }
  }

  // epilogue: Wo split (reuses S / overlays dead loop scratch), MFMA logits, lsm
  cvt_k<<<dim3(4096), 256, 0, stream>>>(Wo, Wohi, Wolo, VOCAB*1024);
  {
    TM p; p.Ahi = AHhi; p.Alo = AHlo; p.Bhi = Wohi; p.Blo = Wolo;
    p.tgt = nullptr; p.bias = bo; p.out = out;
    p.ldc = VOCAB; p.M = NSTEP*BATCH; p.ntile_n = 250;
    tile_k<32,0><<<dim3(8000), 256, 0, stream>>>(p);
  }
  lsm_k<<<dim3(BATCH, NSTEP), 512, 0, stream>>>(out, words);
}

// Round 14
// 6000.047 us; speedup vs baseline: 2.0996x; 1.0103x over previous
//
#include <hip/hip_runtime.h>
#include <math.h>

#define VOCAB 32000
#define EMBD  512
#define HID   1024
#define BATCH 32
#define SEQ   64
#define TENC  64
#define NSTEP 63
#define G4    4096

typedef __attribute__((ext_vector_type(8))) short short8;
typedef __attribute__((ext_vector_type(4))) float f32x4;
typedef __attribute__((ext_vector_type(4))) unsigned short us4;
typedef unsigned short u16;

__device__ __forceinline__ float4 ld4(const float* p) {
  return *reinterpret_cast<const float4*>(p);
}
__device__ __forceinline__ u16 f2bf(float x) {
  unsigned u = __float_as_uint(x);
  return (u16)((u + 0x7fffu + ((u >> 16) & 1u)) >> 16);
}
__device__ __forceinline__ float bf2f(u16 h) {
  return __uint_as_float(((unsigned)h) << 16);
}

// ===== MFMA 32x32 tile core, NW waves K-split (validated R11 @ NW=4) =====
// res: [NW][32][33] fp32 partials.
// MODE 0: K=2048, X=[Xa|Xb]; W row r -> (r>>3)*1024+nt*8+(r&7), stride 2048
// MODE 1: K=1024, X=Xa;     W row nt*32+r, stride 1024
template<int MODE, int NW>
__device__ __forceinline__ void mfma32(
    const u16* __restrict__ Xahi, const u16* __restrict__ Xalo,
    const u16* __restrict__ Xbhi, const u16* __restrict__ Xblo,
    const u16* __restrict__ Whi,  const u16* __restrict__ Wlo,
    int nt, float* res)
{
  const int tid = threadIdx.x;
  const int w = tid >> 6, l = tid & 63;
  const int c = l & 15, koct = l >> 4;
  constexpr int K   = (MODE == 0) ? 2048 : 1024;
  constexpr int WS  = (MODE == 0) ? 2048 : 1024;
  constexpr int SPW = K / 32 / NW;
  const int r0 = c, r1 = 16 + c;
  const int wr0 = (MODE == 0) ? ((r0 >> 3)*1024 + nt*8 + (r0 & 7)) : (nt*32 + r0);
  const int wr1 = (MODE == 0) ? ((r1 >> 3)*1024 + nt*8 + (r1 & 7)) : (nt*32 + r1);
  const u16* bh0 = Whi + (size_t)wr0 * WS;
  const u16* bh1 = Whi + (size_t)wr1 * WS;
  const u16* bl0 = Wlo + (size_t)wr0 * WS;
  const u16* bl1 = Wlo + (size_t)wr1 * WS;

  auto ldA = [&](int m, int kg, int lo) -> short8 {
    const u16* base;
    if (MODE == 0 && kg >= 1024) base = lo ? Xblo : Xbhi;
    else                         base = lo ? Xalo : Xahi;
    const int b = m*16 + c;
    return *reinterpret_cast<const short8*>(base + b*1024 + (kg & 1023));
  };

  f32x4 acc[2][2];
  #pragma unroll
  for (int m = 0; m < 2; ++m)
    #pragma unroll
    for (int n = 0; n < 2; ++n) acc[m][n] = (f32x4){0.f,0.f,0.f,0.f};

  const int s0 = w * SPW;
  short8 Ah[2], Al[2], Bh[2], Bl[2];
  {
    const int kg = s0*32 + koct*8;
    Ah[0]=ldA(0,kg,0); Ah[1]=ldA(1,kg,0); Al[0]=ldA(0,kg,1); Al[1]=ldA(1,kg,1);
    Bh[0]=*reinterpret_cast<const short8*>(bh0+kg);
    Bh[1]=*reinterpret_cast<const short8*>(bh1+kg);
    Bl[0]=*reinterpret_cast<const short8*>(bl0+kg);
    Bl[1]=*reinterpret_cast<const short8*>(bl1+kg);
  }
  for (int s = s0; s < s0 + SPW; ++s) {
    short8 nAh[2], nAl[2], nBh[2], nBl[2];
    if (s + 1 < s0 + SPW) {
      const int kg = (s+1)*32 + koct*8;
      nAh[0]=ldA(0,kg,0); nAh[1]=ldA(1,kg,0); nAl[0]=ldA(0,kg,1); nAl[1]=ldA(1,kg,1);
      nBh[0]=*reinterpret_cast<const short8*>(bh0+kg);
      nBh[1]=*reinterpret_cast<const short8*>(bh1+kg);
      nBl[0]=*reinterpret_cast<const short8*>(bl0+kg);
      nBl[1]=*reinterpret_cast<const short8*>(bl1+kg);
    }
    #pragma unroll
    for (int n = 0; n < 2; ++n)
      #pragma unroll
      for (int m = 0; m < 2; ++m) {
        acc[m][n] = __builtin_amdgcn_mfma_f32_16x16x32_bf16(Ah[m], Bh[n], acc[m][n], 0, 0, 0);
        acc[m][n] = __builtin_amdgcn_mfma_f32_16x16x32_bf16(Ah[m], Bl[n], acc[m][n], 0, 0, 0);
        acc[m][n] = __builtin_amdgcn_mfma_f32_16x16x32_bf16(Al[m], Bh[n], acc[m][n], 0, 0, 0);
      }
    #pragma unroll
    for (int i = 0; i < 2; ++i) { Ah[i]=nAh[i]; Al[i]=nAl[i]; Bh[i]=nBh[i]; Bl[i]=nBl[i]; }
  }
  // C layout: col = lane&15, row = (lane>>4)*4 + reg  (validated)
  #pragma unroll
  for (int m = 0; m < 2; ++m)
    #pragma unroll
    for (int n = 0; n < 2; ++n)
      #pragma unroll
      for (int r = 0; r < 4; ++r) {
        const int b = m*16 + koct*4 + r;
        const int rr = n*16 + c;
        res[w*1056 + b*33 + rr] = acc[m][n][r];
      }
}

// ===== L1/L2: gates + cell, 512 thr / 8-wave K-split =====
struct GKM {
  const u16 *Xahi, *Xalo, *Xbhi, *Xblo;
  const u16 *Whi, *Wlo;
  const float* bsum; const float* gembt;
  float* c; u16 *hhi; u16 *hlo;
};

template<int HASGEMB>
__global__ __launch_bounds__(512) void gates_mfma_k(GKM P) {
  __shared__ float res[8*1056];
  mfma32<0,8>(P.Xahi, P.Xalo, P.Xbhi, P.Xblo, P.Whi, P.Wlo, blockIdx.x, res);
  __syncthreads();
  const int tid = threadIdx.x;
  if (tid < 256) {
    const int b = tid >> 3, j = tid & 7;
    const int n = blockIdx.x*8 + j;
    float g4[4];
    #pragma unroll
    for (int g = 0; g < 4; ++g) {
      const int r = g*8 + j;
      float s = P.bsum[g*1024 + n];
      #pragma unroll
      for (int w = 0; w < 8; ++w) s += res[w*1056 + b*33 + r];
      if (HASGEMB) s += P.gembt[(size_t)b*G4 + g*1024 + n];
      g4[g] = s;
    }
    const float si = 1.f/(1.f+expf(-g4[0]));
    const float sf = 1.f/(1.f+expf(-g4[1]));
    const float so = 1.f/(1.f+expf(-g4[3]));
    const int i = b*HID + n;
    const float cn = sf*P.c[i] + si*tanhf(g4[2]);
    P.c[i] = cn;
    const float h = so*tanhf(cn);
    const u16 hh = f2bf(h);
    P.hhi[i] = hh;
    P.hlo[i] = f2bf(h - bf2f(hh));
  }
}

// ===== L3: proj, 512 thr / 8-wave K-split =====
struct PKM {
  const u16 *Xhi, *Xlo; const u16 *Whi, *Wlo; float* Pq;
};

__global__ __launch_bounds__(512) void proj_mfma_k(PKM P) {
  __shared__ float res[8*1056];
  mfma32<1,8>(P.Xhi, P.Xlo, nullptr, nullptr, P.Whi, P.Wlo, blockIdx.x, res);
  __syncthreads();
  const int tid = threadIdx.x;
  #pragma unroll
  for (int q = 0; q < 2; ++q) {
    const int o = q*512 + tid;
    const int b = o >> 5, r = o & 31;
    float s = 0.f;
    #pragma unroll
    for (int w = 0; w < 8; ++w) s += res[w*1056 + b*33 + r];
    P.Pq[(size_t)b*2048 + blockIdx.x*32 + r] = s;
  }
}

// ===== L4: attention (R11/R13, validated) =====
struct AKM {
  const float* Pq; const float* PreAC; const float* va; const float* bc;
  u16* AHthi; u16* AHtlo;
};

__global__ __launch_bounds__(1024) void attn_k(AKM P) {
  __shared__ float QS[HID];
  __shared__ float sw[TENC];
  __shared__ float W64[TENC];
  const int b = blockIdx.x;
  const int tid = threadIdx.x;
  QS[tid] = P.Pq[(size_t)b*2048 + tid];
  __syncthreads();
  const int lane = tid & 63, wid = tid >> 6;    // 16 waves
  float vreg[16];
  #pragma unroll
  for (int i2 = 0; i2 < 16; ++i2) vreg[i2] = P.va[lane + 64*i2];
  #pragma unroll
  for (int j = 0; j < 4; ++j) {
    const int te = wid*4 + j;
    const float* pr = P.PreAC + ((size_t)te*BATCH + b)*2048;
    float s = 0.f;
    #pragma unroll
    for (int i2 = 0; i2 < 16; ++i2) {
      const int idx = lane + 64*i2;
      s += vreg[i2] * tanhf(QS[idx] + pr[idx]);
    }
    #pragma unroll
    for (int off = 32; off; off >>= 1) s += __shfl_xor(s, off);
    if (lane == 0) sw[te] = s;
  }
  __syncthreads();
  if (tid < TENC) {
    const float v = sw[tid];
    float mx = v;
    #pragma unroll
    for (int off = 32; off; off >>= 1) mx = fmaxf(mx, __shfl_xor(mx, off));
    const float e = expf(v - mx);
    float sum = e;
    #pragma unroll
    for (int off = 32; off; off >>= 1) sum += __shfl_xor(sum, off);
    W64[tid] = e / sum;
  }
  __syncthreads();
  const int hh = tid;
  float acc = 0.f;
  #pragma unroll 8
  for (int te = 0; te < TENC; ++te)
    acc += W64[te] * P.PreAC[((size_t)te*BATCH + b)*2048 + HID + hh];
  const float hc = P.Pq[(size_t)b*2048 + HID + hh] + P.bc[hh];
  const float ah = tanhf(acc + hc);
  const u16 ahh = f2bf(ah);
  P.AHthi[(size_t)b*HID + hh] = ahh;
  P.AHtlo[(size_t)b*HID + hh] = f2bf(ah - bf2f(ahh));
}

// ===== generalized split-bf16 MFMA tile (validated R13) =====
struct TM {
  const u16 *Ahi, *Alo, *Bhi, *Blo;
  const int* tgt; const float* bias;
  float* out; int ldc, M, ntile_n;
};

template<int NC, int AMODE>
__global__ __launch_bounds__(256) void tile_k(TM P) {
  __shared__ float smemf[6144];
  u16* sA = (u16*)smemf;          // [2][4][64][8]
  u16* sB = sA + 4096;            // [2][4][128][8]
  constexpr int K = NC * 32;
  const int tile = blockIdx.x;
  const int mi = tile / P.ntile_n, ni = tile % P.ntile_n;
  const int m0 = mi * 64, n0 = ni * 128;
  const int tid = threadIdx.x;
  const int w = tid >> 6, l = tid & 63;
  const int mb = (w & 1) * 32, nb = (w >> 1) * 64;
  f32x4 acc[2][4];
  #pragma unroll
  for (int mt = 0; mt < 2; ++mt)
    #pragma unroll
    for (int nt = 0; nt < 4; ++nt) acc[mt][nt] = (f32x4){0.f,0.f,0.f,0.f};

  const int arow = tid >> 2, akg = tid & 3;
  const int brow = tid >> 1, bkg = (tid & 1) * 2;
  size_t arbase;
  if (AMODE == 1) {
    const int row = m0 + arow;
    const int tok = P.tgt[(row & 31)*SEQ + (row >> 5)];
    arbase = (size_t)tok * K;
  } else {
    arbase = (size_t)(m0 + arow) * K;
  }
  const size_t brbase = (size_t)(n0 + brow) * K;

  short8 pah, pal, pbh0, pbh1, pbl0, pbl1;
  {
    const size_t ao = arbase + akg*8;
    const size_t bo0 = brbase + bkg*8;
    pah  = *reinterpret_cast<const short8*>(P.Ahi + ao);
    pal  = *reinterpret_cast<const short8*>(P.Alo + ao);
    pbh0 = *reinterpret_cast<const short8*>(P.Bhi + bo0);
    pbh1 = *reinterpret_cast<const short8*>(P.Bhi + bo0 + 8);
    pbl0 = *reinterpret_cast<const short8*>(P.Blo + bo0);
    pbl1 = *reinterpret_cast<const short8*>(P.Blo + bo0 + 8);
  }
  for (int kc = 0; kc < NC; ++kc) {
    __syncthreads();
    *reinterpret_cast<short8*>(sA + ((0*4 + akg)*64 + arow)*8) = pah;
    *reinterpret_cast<short8*>(sA + ((1*4 + akg)*64 + arow)*8) = pal;
    *reinterpret_cast<short8*>(sB + ((0*4 + bkg  )*128 + brow)*8) = pbh0;
    *reinterpret_cast<short8*>(sB + ((0*4 + bkg+1)*128 + brow)*8) = pbh1;
    *reinterpret_cast<short8*>(sB + ((1*4 + bkg  )*128 + brow)*8) = pbl0;
    *reinterpret_cast<short8*>(sB + ((1*4 + bkg+1)*128 + brow)*8) = pbl1;
    __syncthreads();
    if (kc + 1 < NC) {
      const size_t ao = arbase + (kc+1)*32 + akg*8;
      const size_t bo0 = brbase + (kc+1)*32 + bkg*8;
      pah  = *reinterpret_cast<const short8*>(P.Ahi + ao);
      pal  = *reinterpret_cast<const short8*>(P.Alo + ao);
      pbh0 = *reinterpret_cast<const short8*>(P.Bhi + bo0);
      pbh1 = *reinterpret_cast<const short8*>(P.Bhi + bo0 + 8);
      pbl0 = *reinterpret_cast<const short8*>(P.Blo + bo0);
      pbl1 = *reinterpret_cast<const short8*>(P.Blo + bo0 + 8);
    }
    const int kg = l >> 4, rr = l & 15;
    short8 ah[2], al[2];
    #pragma unroll
    for (int mt = 0; mt < 2; ++mt) {
      ah[mt] = *reinterpret_cast<const short8*>(sA + ((0*4 + kg)*64 + mb + mt*16 + rr)*8);
      al[mt] = *reinterpret_cast<const short8*>(sA + ((1*4 + kg)*64 + mb + mt*16 + rr)*8);
    }
    #pragma unroll
    for (int nt = 0; nt < 4; ++nt) {
      const short8 bh = *reinterpret_cast<const short8*>(sB + ((0*4 + kg)*128 + nb + nt*16 + rr)*8);
      const short8 bl = *reinterpret_cast<const short8*>(sB + ((1*4 + kg)*128 + nb + nt*16 + rr)*8);
      #pragma unroll
      for (int mt = 0; mt < 2; ++mt) {
        acc[mt][nt] = __builtin_amdgcn_mfma_f32_16x16x32_bf16(ah[mt], bh, acc[mt][nt], 0, 0, 0);
        acc[mt][nt] = __builtin_amdgcn_mfma_f32_16x16x32_bf16(ah[mt], bl, acc[mt][nt], 0, 0, 0);
        acc[mt][nt] = __builtin_amdgcn_mfma_f32_16x16x32_bf16(al[mt], bh, acc[mt][nt], 0, 0, 0);
      }
    }
  }
  #pragma unroll
  for (int mt = 0; mt < 2; ++mt) {
    #pragma unroll
    for (int nt = 0; nt < 4; ++nt) {
      #pragma unroll
      for (int r = 0; r < 4; ++r) {
        const int row = m0 + mb + mt*16 + (l >> 4)*4 + r;
        const int col = n0 + nb + nt*16 + (l & 15);
        if (row < P.M) {
          const float bb = P.bias ? P.bias[col] : 0.f;
          P.out[(size_t)row*P.ldc + col] = acc[mt][nt][r] + bb;
        }
      }
    }
  }
}

// ===== split/pack device bodies (grid-stride within a role) =====
__device__ __forceinline__ void cvt_body(const float* __restrict__ src,
                                         u16* __restrict__ hi, u16* __restrict__ lo,
                                         int n, int bid, int nblk) {
  int i = (bid*256 + (int)threadIdx.x) * 4;
  const int stride = nblk * 256 * 4;
  for (; i < n; i += stride) {
    const float4 v = ld4(src + i);
    us4 h, l;
    h.x = f2bf(v.x); l.x = f2bf(v.x - bf2f(h.x));
    h.y = f2bf(v.y); l.y = f2bf(v.y - bf2f(h.y));
    h.z = f2bf(v.z); l.z = f2bf(v.z - bf2f(h.z));
    h.w = f2bf(v.w); l.w = f2bf(v.w - bf2f(h.w));
    *reinterpret_cast<us4*>(hi + i) = h;
    *reinterpret_cast<us4*>(lo + i) = l;
  }
}

// 0: [4096][2048] <- [Wih0[:,512:1536] | Whh0] ; 1: <- [Wih1 | Whh1]
// 2: [2048][1024] <- [Wa1;Wc1] ; 3: <- [Wa2;Wc2] ; 4: [4096][512] <- Wih0[:,0:512]
template<int MODE>
__device__ __forceinline__ void pk_body(const float* __restrict__ A,
                                        const float* __restrict__ B,
                                        u16* __restrict__ hi, u16* __restrict__ lo,
                                        int bid, int nblk) {
  constexpr int ROWS = (MODE == 2 || MODE == 3) ? 2048 : 4096;
  constexpr int K    = (MODE == 2 || MODE == 3) ? 1024 : (MODE == 4 ? 512 : 2048);
  const size_t total = (size_t)ROWS * (K/4);
  for (size_t i = (size_t)bid*256 + threadIdx.x; i < total; i += (size_t)nblk*256) {
    const int row = (int)(i / (K/4));
    const int k = (int)(i % (K/4)) * 4;
    float4 v;
    if (MODE == 0) v = (k < 1024) ? ld4(A + (size_t)row*1536 + 512 + k)
                                  : ld4(B + (size_t)row*1024 + (k - 1024));
    else if (MODE == 1) v = (k < 1024) ? ld4(A + (size_t)row*1024 + k)
                                       : ld4(B + (size_t)row*1024 + (k - 1024));
    else if (MODE == 2) v = (row < 1024) ? ld4(A + (size_t)row*2048 + k)
                                         : ld4(B + (size_t)(row - 1024)*2048 + k);
    else if (MODE == 3) v = (row < 1024) ? ld4(A + (size_t)row*2048 + 1024 + k)
                                         : ld4(B + (size_t)(row - 1024)*2048 + 1024 + k);
    else v = ld4(A + (size_t)row*1536 + k);
    us4 h, l;
    h.x = f2bf(v.x); l.x = f2bf(v.x - bf2f(h.x));
    h.y = f2bf(v.y); l.y = f2bf(v.y - bf2f(h.y));
    h.z = f2bf(v.z); l.z = f2bf(v.z - bf2f(h.z));
    h.w = f2bf(v.w); l.w = f2bf(v.w - bf2f(h.w));
    *reinterpret_cast<us4*>(hi + i*4) = h;
    *reinterpret_cast<us4*>(lo + i*4) = l;
  }
}

struct PrepP {
  const float *enc, *emb, *Wa, *Wc, *Wih0, *Whh0, *Wih1, *Whh1;
  u16 *enchi,*enclo,*embhi,*emblo,*WAChi,*WAClo,*W0ehi,*W0elo;
  u16 *W0hi,*W0lo,*W1hi,*W1lo,*WAhi,*WAlo;
};

template<int FAST>
__global__ __launch_bounds__(256) void prep_k(PrepP P) {
  const int bid = blockIdx.x;
  if (FAST) {
    if      (bid < 256)  cvt_body(P.enc, P.enchi, P.enclo, 2048*1024, bid, 256);
    else if (bid < 2304) cvt_body(P.emb, P.embhi, P.emblo, VOCAB*EMBD, bid-256, 2048);
    else if (bid < 2560) pk_body<3>(P.Wa, P.Wc, P.WAChi, P.WAClo, bid-2304, 256);
    else if (bid < 2816) pk_body<4>(P.Wih0, nullptr, P.W0ehi, P.W0elo, bid-2560, 256);
    else if (bid < 3840) pk_body<0>(P.Wih0, P.Whh0, P.W0hi, P.W0lo, bid-2816, 1024);
    else if (bid < 4864) pk_body<1>(P.Wih1, P.Whh1, P.W1hi, P.W1lo, bid-3840, 1024);
    else                 pk_body<2>(P.Wa, P.Wc, P.WAhi, P.WAlo, bid-4864, 256);
  } else {
    if      (bid < 1024) pk_body<0>(P.Wih0, P.Whh0, P.W0hi, P.W0lo, bid, 1024);
    else if (bid < 2048) pk_body<1>(P.Wih1, P.Whh1, P.W1hi, P.W1lo, bid-1024, 1024);
    else                 pk_body<2>(P.Wa, P.Wc, P.WAhi, P.WAlo, bid-2048, 256);
  }
}

// ===== fp32 -> bf16 hi/lo (Wo, post-loop) =====
__global__ __launch_bounds__(256) void cvt_k(const float* __restrict__ src,
                                             u16* __restrict__ hi,
                                             u16* __restrict__ lo, int n) {
  cvt_body(src, hi, lo, n, blockIdx.x, gridDim.x);
}

// ===== fp32 wide GEMM (fallback PreAC / Gemb only) =====
struct WGP {
  const float* A; const float* W; const float* W2; const float* bias;
  const int* tgt; const float* emb;
  float* C; int ldc;
};

template<int WM>
__device__ __forceinline__ float4 ldWL(const WGP& P, int r, int k) {
  if (WM == 2) return ld4(P.W + (size_t)r * (EMBD + HID) + k);
  if (r < HID) return ld4(P.W  + (size_t)r * (2*HID) + HID + k);
  return ld4(P.W2 + (size_t)(r - HID) * (2*HID) + HID + k);
}

template<int WM>
__device__ __forceinline__ float4 ldAL(const WGP& P, int row, int k) {
  if (WM == 2) {
    const int tok = P.tgt[(row & 31) * SEQ + (row >> 5)];
    return ld4(P.emb + (size_t)tok * EMBD + k);
  }
  return ld4(P.A + (size_t)row * 1024 + k);
}

template<int WM>
__global__ __launch_bounds__(256, 2) void gemmL(WGP P) {
  constexpr int KK = (WM == 2) ? 512 : 1024;
  __shared__ float At[32*36];
  __shared__ float Wt[32*260];
  const int tid = threadIdx.x;
  const int m0 = blockIdx.x * 32;
  const int n0 = blockIdx.y * 256;
  const int lr = tid >> 3, lc = (tid & 7) << 2;
  const int tn = tid & 31, tm = tid >> 5;
  float acc[4][8];
  #pragma unroll
  for (int i = 0; i < 4; ++i)
    #pragma unroll
    for (int x = 0; x < 8; ++x) acc[i][x] = 0.f;

  float4 av = ldAL<WM>(P, m0 + lr, lc);
  float4 wv[8];
  #pragma unroll
  for (int it = 0; it < 8; ++it) wv[it] = ldWL<WM>(P, n0 + lr + it*32, lc);

  for (int k0 = 0; k0 < KK; k0 += 32) {
    float4 avn, wvn[8];
    if (k0 + 32 < KK) {
      avn = ldAL<WM>(P, m0 + lr, k0 + 32 + lc);
      #pragma unroll
      for (int it = 0; it < 8; ++it) wvn[it] = ldWL<WM>(P, n0 + lr + it*32, k0 + 32 + lc);
    }
    __syncthreads();
    At[(lc+0)*36+lr]=av.x; At[(lc+1)*36+lr]=av.y; At[(lc+2)*36+lr]=av.z; At[(lc+3)*36+lr]=av.w;
    #pragma unroll
    for (int it = 0; it < 8; ++it) {
      const int r = lr + it*32;
      Wt[(lc+0)*260+r]=wv[it].x; Wt[(lc+1)*260+r]=wv[it].y;
      Wt[(lc+2)*260+r]=wv[it].z; Wt[(lc+3)*260+r]=wv[it].w;
    }
    __syncthreads();
    #pragma unroll
    for (int kk = 0; kk < 32; ++kk) {
      const float4 a  = *reinterpret_cast<const float4*>(&At[kk*36 + tm*4]);
      const float4 w0 = *reinterpret_cast<const float4*>(&Wt[kk*260 + tn*8]);
      const float4 w1 = *reinterpret_cast<const float4*>(&Wt[kk*260 + tn*8 + 4]);
      #pragma unroll
      for (int i = 0; i < 4; ++i) {
        const float ai = (&a.x)[i];
        acc[i][0]+=ai*w0.x; acc[i][1]+=ai*w0.y; acc[i][2]+=ai*w0.z; acc[i][3]+=ai*w0.w;
        acc[i][4]+=ai*w1.x; acc[i][5]+=ai*w1.y; acc[i][6]+=ai*w1.z; acc[i][7]+=ai*w1.w;
      }
    }
    av = avn;
    #pragma unroll
    for (int it = 0; it < 8; ++it) wv[it] = wvn[it];
  }
  const int na = n0 + tn*8, ma = m0 + tm*4;
  float bb[8];
  #pragma unroll
  for (int x = 0; x < 8; ++x) {
    if (WM == 1) bb[x] = (na + x < HID) ? P.bias[na+x] : 0.f;
    else         bb[x] = 0.f;
  }
  #pragma unroll
  for (int i = 0; i < 4; ++i)
    #pragma unroll
    for (int x = 0; x < 8; ++x)
      P.C[(size_t)(ma+i)*P.ldc + na + x] = acc[i][x] + bb[x];
}

// ===== per-(b,t) log-softmax + argmax, online single-pass =====
__global__ __launch_bounds__(512) void lsm_k(float* __restrict__ out,
                                             float* __restrict__ words) {
  const int b = blockIdx.x;
  const int t = blockIdx.y;
  float* row = out + ((size_t)t*BATCH + b)*VOCAB;
  const int tid = threadIdx.x;
  float m = -INFINITY, s = 0.f; int mi = 0;
  for (int v = tid; v < VOCAB; v += 512) {
    const float x = row[v];
    if (x > m) { s = s * expf(m - x) + 1.f; m = x; mi = v; }
    else s += expf(x - m);
  }
  __shared__ float sm[512]; __shared__ float sv[512]; __shared__ int si[512];
  sm[tid] = m; sv[tid] = s; si[tid] = mi;
  __syncthreads();
  for (int st = 256; st; st >>= 1) {
    if (tid < st) {
      const float om = sm[tid+st], os = sv[tid+st]; const int oi = si[tid+st];
      if (om > sm[tid]) {
        sv[tid] = os + sv[tid] * expf(sm[tid] - om);
        sm[tid] = om; si[tid] = oi;
      } else if (om == sm[tid]) {
        sv[tid] += os;
        if (oi < si[tid]) si[tid] = oi;
      } else {
        sv[tid] += os * expf(om - sm[tid]);
      }
    }
    __syncthreads();
  }
  const float lse = logf(sv[0]) + sm[0];
  const int amax = si[0];
  for (int v = tid; v < VOCAB; v += 512) row[v] = row[v] - lse;
  if (tid == 0) words[(size_t)t*BATCH + b] = (float)amax;
}

// ===== init =====
__global__ __launch_bounds__(256) void init_k(const float* __restrict__ enc_h,
                                              const float* __restrict__ enc_c,
                                              const float* __restrict__ bih0,
                                              const float* __restrict__ bhh0,
                                              const float* __restrict__ bih1,
                                              const float* __restrict__ bhh1,
                                              const float* __restrict__ ba,
                                              float* c0, float* c1,
                                              u16* h0hi, u16* h0lo, u16* h1hi, u16* h1lo,
                                              u16* zahhi, u16* zahlo,
                                              float* bsum0, float* bsum1,
                                              float* bias2048) {
  const int i = blockIdx.x*256 + threadIdx.x;
  if (i < BATCH*HID) {
    c0[i] = enc_c[i]; c1[i] = enc_c[BATCH*HID + i];
    const float v0 = enc_h[i];
    const u16 h0 = f2bf(v0);
    h0hi[i] = h0; h0lo[i] = f2bf(v0 - bf2f(h0));
    const float v1 = enc_h[BATCH*HID + i];
    const u16 h1 = f2bf(v1);
    h1hi[i] = h1; h1lo[i] = f2bf(v1 - bf2f(h1));
    zahhi[i] = 0; zahlo[i] = 0;
  }
  if (i < G4) {
    bsum0[i] = bih0[i] + bhh0[i];
    bsum1[i] = bih1[i] + bhh1[i];
  }
  if (i < 2048) bias2048[i] = (i < HID) ? ba[i] : 0.f;
}

extern "C" void kernel_launch(void* const* d_in, const int* in_sizes, int n_in,
                              void* d_out, int out_size, void* d_ws, size_t ws_size,
                              hipStream_t stream) {
  const int*   tgt   = (const int*)d_in[0];
  const float* enc_h = (const float*)d_in[1];
  const float* enc_c = (const float*)d_in[2];
  const float* enc   = (const float*)d_in[3];
  const float* emb   = (const float*)d_in[4];
  const float* Wih0  = (const float*)d_in[5];
  const float* Whh0  = (const float*)d_in[6];
  const float* bih0  = (const float*)d_in[7];
  const float* bhh0  = (const float*)d_in[8];
  const float* Wih1  = (const float*)d_in[9];
  const float* Whh1  = (const float*)d_in[10];
  const float* bih1  = (const float*)d_in[11];
  const float* bhh1  = (const float*)d_in[12];
  const float* Wa    = (const float*)d_in[13];
  const float* ba    = (const float*)d_in[14];
  const float* va    = (const float*)d_in[15];
  const float* Wc    = (const float*)d_in[16];
  const float* bc    = (const float*)d_in[17];
  const float* Wo    = (const float*)d_in[18];
  const float* bo    = (const float*)d_in[19];

  // ---- workspace layout (R13) ----
  char* base = (char*)d_ws;
  size_t cur = 0;
  auto take = [&](size_t bytes) { char* p = base + cur; cur = (cur + bytes + 63) & ~(size_t)63; return p; };

  u16* AHhi = (u16*)take((size_t)2048*1024*2);
  u16* AHlo = (u16*)take((size_t)2048*1024*2);
  float* PreAC = (float*)take((size_t)2048*2048*4);
  float* Gemb  = (float*)take((size_t)NSTEP*BATCH*G4*4);
  float* Pq    = (float*)take((size_t)BATCH*2048*4);
  float* c0    = (float*)take(BATCH*HID*4);
  float* c1v   = (float*)take(BATCH*HID*4);
  float* bsum0 = (float*)take(G4*4);
  float* bsum1 = (float*)take(G4*4);
  float* bias2048 = (float*)take(2048*4);
  u16* W0hi = (u16*)take((size_t)4096*2048*2);
  u16* W0lo = (u16*)take((size_t)4096*2048*2);
  u16* W1hi = (u16*)take((size_t)4096*2048*2);
  u16* W1lo = (u16*)take((size_t)4096*2048*2);
  u16* WAhi = (u16*)take((size_t)2048*1024*2);
  u16* WAlo = (u16*)take((size_t)2048*1024*2);
  u16* h0Ahi = (u16*)take(BATCH*HID*2);
  u16* h0Alo = (u16*)take(BATCH*HID*2);
  u16* h0Bhi = (u16*)take(BATCH*HID*2);
  u16* h0Blo = (u16*)take(BATCH*HID*2);
  u16* h1Ahi = (u16*)take(BATCH*HID*2);
  u16* h1Alo = (u16*)take(BATCH*HID*2);
  u16* h1Bhi = (u16*)take(BATCH*HID*2);
  u16* h1Blo = (u16*)take(BATCH*HID*2);
  u16* zahhi = (u16*)take(BATCH*HID*2);
  u16* zahlo = (u16*)take(BATCH*HID*2);
  char* S = take((size_t)VOCAB*1024*2*2);          // 131 MB shared scratch
  const bool fast = ws_size >= cur;

  u16* enchi = (u16*)S;
  u16* enclo = enchi + (size_t)2048*1024;
  u16* embhi = enclo + (size_t)2048*1024;
  u16* emblo = embhi + (size_t)VOCAB*EMBD;
  u16* WAChi = emblo + (size_t)VOCAB*EMBD;
  u16* WAClo = WAChi + (size_t)2048*1024;
  u16* W0ehi = WAClo + (size_t)2048*1024;
  u16* W0elo = W0ehi + (size_t)4096*512;
  u16* Wohi = fast ? (u16*)S : (u16*)PreAC;
  u16* Wolo = Wohi + (size_t)VOCAB*1024;

  float* out   = (float*)d_out;
  float* words = out + (size_t)NSTEP*BATCH*VOCAB;

  init_k<<<dim3(128), 256, 0, stream>>>(enc_h, enc_c, bih0, bhh0, bih1, bhh1, ba,
                                        c0, c1v, h0Ahi, h0Alo, h1Ahi, h1Alo,
                                        zahhi, zahlo, bsum0, bsum1, bias2048);

  { // consolidated splits/packs (one launch)
    PrepP p;
    p.enc = enc; p.emb = emb; p.Wa = Wa; p.Wc = Wc;
    p.Wih0 = Wih0; p.Whh0 = Whh0; p.Wih1 = Wih1; p.Whh1 = Whh1;
    p.enchi = enchi; p.enclo = enclo; p.embhi = embhi; p.emblo = emblo;
    p.WAChi = WAChi; p.WAClo = WAClo; p.W0ehi = W0ehi; p.W0elo = W0elo;
    p.W0hi = W0hi; p.W0lo = W0lo; p.W1hi = W1hi; p.W1lo = W1lo;
    p.WAhi = WAhi; p.WAlo = WAlo;
    if (fast) prep_k<1><<<dim3(5120), 256, 0, stream>>>(p);
    else      prep_k<0><<<dim3(2304), 256, 0, stream>>>(p);
  }

  if (fast) {
    { // PreAC = enc @ [Wa2;Wc2]^T + [ba;0]   (MFMA tiles)
      TM p; p.Ahi = enchi; p.Alo = enclo; p.Bhi = WAChi; p.Blo = WAClo;
      p.tgt = nullptr; p.bias = bias2048; p.out = PreAC;
      p.ldc = 2048; p.M = 2048; p.ntile_n = 16;
      tile_k<32,0><<<dim3(512), 256, 0, stream>>>(p);
    }
    { // Gemb = emb[tok] @ Wih0[:, :512]^T   (MFMA tiles, gathered A)
      TM p; p.Ahi = embhi; p.Alo = emblo; p.Bhi = W0ehi; p.Blo = W0elo;
      p.tgt = tgt; p.bias = nullptr; p.out = Gemb;
      p.ldc = G4; p.M = NSTEP*BATCH; p.ntile_n = 32;
      tile_k<16,1><<<dim3(1024), 256, 0, stream>>>(p);
    }
  } else {
    { WGP p = {}; p.A = enc; p.W = Wa; p.W2 = Wc; p.bias = ba; p.C = PreAC; p.ldc = 2048;
      gemmL<1><<<dim3(64, 8), 256, 0, stream>>>(p); }
    { WGP p = {}; p.W = Wih0; p.tgt = tgt; p.emb = emb; p.C = Gemb; p.ldc = G4;
      gemmL<2><<<dim3(NSTEP*BATCH/32, G4/256), 256, 0, stream>>>(p); }
  }

  for (int t = 0; t < NSTEP; ++t) {
    const u16* ahphi = t ? (AHhi + (size_t)(t-1)*BATCH*HID) : zahhi;
    const u16* ahplo = t ? (AHlo + (size_t)(t-1)*BATCH*HID) : zahlo;
    const u16* h0phi = (t & 1) ? h0Bhi : h0Ahi;
    const u16* h0plo = (t & 1) ? h0Blo : h0Alo;
    u16* h0chi = (t & 1) ? h0Ahi : h0Bhi;
    u16* h0clo = (t & 1) ? h0Alo : h0Blo;
    const u16* h1phi = (t & 1) ? h1Bhi : h1Ahi;
    const u16* h1plo = (t & 1) ? h1Blo : h1Alo;
    u16* h1chi = (t & 1) ? h1Ahi : h1Bhi;
    u16* h1clo = (t & 1) ? h1Alo : h1Blo;

    { // L1: gates0 + cell0
      GKM p = {};
      p.Xahi = ahphi; p.Xalo = ahplo; p.Xbhi = h0phi; p.Xblo = h0plo;
      p.Whi = W0hi; p.Wlo = W0lo;
      p.bsum = bsum0; p.gembt = Gemb + (size_t)t*BATCH*G4;
      p.c = c0; p.hhi = h0chi; p.hlo = h0clo;
      gates_mfma_k<1><<<dim3(128), 512, 0, stream>>>(p);
    }
    { // L2: gates1 + cell1
      GKM p = {};
      p.Xahi = h0chi; p.Xalo = h0clo; p.Xbhi = h1phi; p.Xblo = h1plo;
      p.Whi = W1hi; p.Wlo = W1lo;
      p.bsum = bsum1; p.gembt = nullptr;
      p.c = c1v; p.hhi = h1chi; p.hlo = h1clo;
      gates_mfma_k<0><<<dim3(128), 512, 0, stream>>>(p);
    }
    { // L3: Pq = h1_t · [Wa1;Wc1]^T
      PKM p; p.Xhi = h1chi; p.Xlo = h1clo; p.Whi = WAhi; p.Wlo = WAlo; p.Pq = Pq;
      proj_mfma_k<<<dim3(64), 512, 0, stream>>>(p);
    }
    { // L4: attention -> AH[t] (bf16 hi/lo)
      AKM p; p.Pq = Pq; p.PreAC = PreAC; p.va = va; p.bc = bc;
      p.AHthi = AHhi + (size_t)t*BATCH*HID;
      p.AHtlo = AHlo + (size_t)t*BATCH*HID;
      attn_k<<<dim3(BATCH), 1024, 0, stream>>>(p);
    }
  }

  // epilogue: Wo split (reuses S / overlays dead loop scratch), MFMA logits, lsm
  cvt_k<<<dim3(4096), 256, 0, stream>>>(Wo, Wohi, Wolo, VOCAB*1024);
  {
    TM p; p.Ahi = AHhi; p.Alo = AHlo; p.Bhi = Wohi; p.Blo = Wolo;
    p.tgt = nullptr; p.bias = bo; p.out = out;
    p.ldc = VOCAB; p.M = NSTEP*BATCH; p.ntile_n = 250;
    tile_k<32,0><<<dim3(8000), 256, 0, stream>>>(p);
  }
  lsm_k<<<dim3(BATCH, NSTEP), 512, 0, stream>>>(out, words);
}